// Round 11
// baseline (608.253 us; speedup 1.0000x reference)
//
#include <hip/hip_runtime.h>
#include <hip/hip_bf16.h>

#define N_NODES 50000
#define E_EDGES 800000
#define IN_F 128
#define HIDF 64
#define HEADS 4
#define OUT_F 40
#define GROUPS 8
#define D_F 256
#define NEG 0.2f
#define LNEPS 1e-5f
#define POOL_CHUNK 128
#define POOL_BLOCKS ((N_NODES + POOL_CHUNK - 1) / POOL_CHUNK)   // 391
#define NB256 ((N_NODES + 255) / 256)                            // 196

// canonical bf16 parameter buffer: element offsets
#define OFF_X    0
#define OFF_EW1  6400000
#define OFF_EB1  6408192
#define OFF_EG   6408256
#define OFF_EBE  6408320
#define OFF_EW2  6408384
#define OFF_EB2  6412480
#define OFF_C0W  6412544
#define OFF_C0AS 6428928
#define OFF_C0AD 6429184
#define OFF_C0B  6429440
#define OFF_C1W  6429696
#define OFF_C1AS 6495232
#define OFF_C1AD 6495488
#define OFF_C1B  6495744
#define OFF_C2W  6496000
#define OFF_C2AS 6561536
#define OFF_C2AD 6561792
#define OFF_C2B  6562048
#define OFF_DW1  6562304
#define OFF_DB1  6578688
#define OFF_DG   6578752
#define OFF_DBE  6578816
#define OFF_DW2  6578880
#define OFF_DB2  6581440
#define CANON_TOT 6581480

__device__ __constant__ int c_off[26] = {
    OFF_X, OFF_EW1, OFF_EB1, OFF_EG, OFF_EBE, OFF_EW2, OFF_EB2,
    OFF_C0W, OFF_C0AS, OFF_C0AD, OFF_C0B,
    OFF_C1W, OFF_C1AS, OFF_C1AD, OFF_C1B,
    OFF_C2W, OFF_C2AS, OFF_C2AD, OFF_C2B,
    OFF_DW1, OFF_DB1, OFF_DG, OFF_DBE, OFF_DW2, OFF_DB2, CANON_TOT};

typedef __attribute__((ext_vector_type(8))) short bf16x8;
typedef __attribute__((ext_vector_type(4))) float f32x4;

__device__ __forceinline__ float bf2f(unsigned short u) {
    union { unsigned int i; float f; } v; v.i = ((unsigned int)u) << 16; return v.f;
}
__device__ __forceinline__ unsigned short f2bf(float f) {
    union { float f; unsigned int i; } v; v.f = f;
    unsigned int r = v.i + 0x7FFF + ((v.i >> 16) & 1);   // RNE
    return (unsigned short)(r >> 16);
}
__device__ __forceinline__ void mac8(float* acc, float w, uint4 u) {
    acc[0] = fmaf(w, bf2f((unsigned short)(u.x & 0xffff)), acc[0]);
    acc[1] = fmaf(w, bf2f((unsigned short)(u.x >> 16)),    acc[1]);
    acc[2] = fmaf(w, bf2f((unsigned short)(u.y & 0xffff)), acc[2]);
    acc[3] = fmaf(w, bf2f((unsigned short)(u.y >> 16)),    acc[3]);
    acc[4] = fmaf(w, bf2f((unsigned short)(u.z & 0xffff)), acc[4]);
    acc[5] = fmaf(w, bf2f((unsigned short)(u.z >> 16)),    acc[5]);
    acc[6] = fmaf(w, bf2f((unsigned short)(u.w & 0xffff)), acc[6]);
    acc[7] = fmaf(w, bf2f((unsigned short)(u.w >> 16)),    acc[7]);
}
__device__ __forceinline__ int dtype_flag(const unsigned short* encg) {
    return (encg[0] == 0x0000 && encg[1] == 0x3F80) ? 1 : 0;
}

// ---------- canonicalize (flag computed inline; fast path for x) ----------
struct SP { const void* q[25]; };
__global__ __launch_bounds__(256) void convert_k(SP sp, unsigned short* __restrict__ canon) {
    int i = blockIdx.x * 256 + threadIdx.x;
    if (i >= CANON_TOT) return;
    int fl = dtype_flag((const unsigned short*)sp.q[3]);   // enc_g
    if (i < OFF_EW1) {
        canon[i] = fl == 0 ? ((const unsigned short*)sp.q[0])[i]
                           : f2bf(((const float*)sp.q[0])[i]);
        return;
    }
    int t = 1;
    while (i >= c_off[t + 1]) ++t;
    int j = i - c_off[t];
    const void* s = sp.q[t];
    canon[i] = fl == 0 ? ((const unsigned short*)s)[j] : f2bf(((const float*)s)[j]);
}

// ---------- weight transposes + layer-0 logit projection P0 = W0·a (64x8) ----------
__global__ void wt_k(const unsigned short* __restrict__ canon,
                     unsigned short* __restrict__ wt0, unsigned short* __restrict__ wt1,
                     unsigned short* __restrict__ wt2, unsigned short* __restrict__ w1t,
                     unsigned short* __restrict__ w2t, unsigned short* __restrict__ p0) {
    int i = blockIdx.x * 256 + threadIdx.x;   // 65536 threads
    if (i < 8192) {
        int k = i >> 6, n = i & 63;
        w1t[n * 128 + k] = canon[OFF_EW1 + k * 64 + n];
    }
    if (i < 4096) {
        int k = i >> 6, n = i & 63;
        w2t[n * 64 + k] = canon[OFF_EW2 + k * 64 + n];
    }
    if (i < 16384) {
        int k = i >> 8, n = i & 255;
        wt0[n * 64 + k] = canon[OFF_C0W + i];
    }
    if (i < 65536) {
        int k = i >> 8, n = i & 255;
        wt1[n * 256 + k] = canon[OFF_C1W + i];
        wt2[n * 256 + k] = canon[OFF_C2W + i];
    }
    if (i < 512) {   // P0[k][out], out = sd*4+h
        int out = i & 7, k = i >> 3;
        int h = out & 3, sd = out >> 2;
        int abase = (sd == 0 ? OFF_C0AS : OFF_C0AD) + h * 64;
        int wbase = OFF_C0W + k * 256 + h * 64;
        float s = 0.f;
        for (int c = 0; c < 64; ++c)
            s = fmaf(bf2f(canon[wbase + c]), bf2f(canon[abase + c]), s);
        p0[k * 8 + out] = f2bf(s);
    }
}

// ---------------- encoder stage 1: T1 = relu(LN(x@w1+b1)), MFMA + fused LN ----------------
__global__ __launch_bounds__(128) void enc1_k(const unsigned short* __restrict__ canon,
                                              const unsigned short* __restrict__ w1t,
                                              unsigned short* __restrict__ T1) {
    const unsigned short* x = canon + OFF_X;
    __shared__ unsigned short As[128 * 72];
    __shared__ unsigned short Bs[64 * 72];
    int tid = threadIdx.x, wave = tid >> 6, lane = tid & 63;
    int q = lane >> 4, l = lane & 15;
    int row0 = blockIdx.x * 128;
    f32x4 acc[4][4];
#pragma unroll
    for (int a = 0; a < 4; ++a)
#pragma unroll
        for (int b = 0; b < 4; ++b) acc[a][b] = (f32x4){0.f, 0.f, 0.f, 0.f};
    for (int kb = 0; kb < IN_F; kb += 64) {
#pragma unroll
        for (int it = 0; it < 8; ++it) {
            int cid = it * 128 + tid;
            int r = cid >> 3, kc = cid & 7;
            int gr = row0 + r;
            uint4 v = make_uint4(0, 0, 0, 0);
            if (gr < N_NODES) v = *(const uint4*)(x + (size_t)gr * IN_F + kb + kc * 8);
            *(uint4*)&As[r * 72 + kc * 8] = v;
        }
#pragma unroll
        for (int it = 0; it < 4; ++it) {
            int cid = it * 128 + tid;
            int r = cid >> 3, kc = cid & 7;
            uint4 w = *(const uint4*)(w1t + (size_t)r * IN_F + kb + kc * 8);
            *(uint4*)&Bs[r * 72 + kc * 8] = w;
        }
        __syncthreads();
#pragma unroll
        for (int ks = 0; ks < 64; ks += 32) {
            bf16x8 af[4], bfr[4];
#pragma unroll
            for (int mt = 0; mt < 4; ++mt)
                af[mt] = *(const bf16x8*)&As[(wave * 64 + mt * 16 + l) * 72 + ks + q * 8];
#pragma unroll
            for (int nt = 0; nt < 4; ++nt)
                bfr[nt] = *(const bf16x8*)&Bs[(nt * 16 + l) * 72 + ks + q * 8];
#pragma unroll
            for (int mt = 0; mt < 4; ++mt)
#pragma unroll
                for (int nt = 0; nt < 4; ++nt)
                    acc[mt][nt] = __builtin_amdgcn_mfma_f32_16x16x32_bf16(
                        af[mt], bfr[nt], acc[mt][nt], 0, 0, 0);
        }
        __syncthreads();
    }
    float b1c[4], gc[4], bec[4];
#pragma unroll
    for (int nt = 0; nt < 4; ++nt) {
        int c = nt * 16 + l;
        b1c[nt] = bf2f(canon[OFF_EB1 + c]);
        gc[nt]  = bf2f(canon[OFF_EG + c]);
        bec[nt] = bf2f(canon[OFF_EBE + c]);
    }
#pragma unroll
    for (int mt = 0; mt < 4; ++mt) {
#pragma unroll
        for (int r = 0; r < 4; ++r) {
            int grow = row0 + wave * 64 + mt * 16 + q * 4 + r;
            float v0 = acc[mt][0][r] + b1c[0];
            float v1 = acc[mt][1][r] + b1c[1];
            float v2 = acc[mt][2][r] + b1c[2];
            float v3 = acc[mt][3][r] + b1c[3];
            float s = v0 + v1 + v2 + v3;
#pragma unroll
            for (int off = 1; off < 16; off <<= 1) s += __shfl_xor(s, off);
            float mean = s * (1.0f / 64.0f);
            float d0 = v0 - mean, d1 = v1 - mean, d2 = v2 - mean, d3 = v3 - mean;
            float vs = d0 * d0 + d1 * d1 + d2 * d2 + d3 * d3;
#pragma unroll
            for (int off = 1; off < 16; off <<= 1) vs += __shfl_xor(vs, off);
            float rstd = rsqrtf(vs * (1.0f / 64.0f) + LNEPS);
            if (grow < N_NODES) {
                unsigned short* trow = T1 + (size_t)grow * HIDF;
                float o0 = gc[0] * d0 * rstd + bec[0]; o0 = fmaxf(o0, 0.f);
                float o1 = gc[1] * d1 * rstd + bec[1]; o1 = fmaxf(o1, 0.f);
                float o2 = gc[2] * d2 * rstd + bec[2]; o2 = fmaxf(o2, 0.f);
                float o3 = gc[3] * d3 * rstd + bec[3]; o3 = fmaxf(o3, 0.f);
                trow[l] = f2bf(o0); trow[16 + l] = f2bf(o1);
                trow[32 + l] = f2bf(o2); trow[48 + l] = f2bf(o3);
            }
        }
    }
}

// ---------------- encoder stage 2: h0 = T1 @ w2 + b2, LDS-staged + fused layer-0 logits ----------------
__global__ __launch_bounds__(128) void enc2_k(const unsigned short* __restrict__ canon,
                                              const unsigned short* __restrict__ T1,
                                              const unsigned short* __restrict__ w2t,
                                              const unsigned short* __restrict__ p0,
                                              unsigned short* __restrict__ h0,
                                              float* __restrict__ alS, float* __restrict__ alD) {
    __shared__ unsigned short As[128 * 72];
    __shared__ unsigned short Bs[64 * 72];   // reused as float p0f[512] after MFMA
    int tid = threadIdx.x, wave = tid >> 6, lane = tid & 63;
    int q = lane >> 4, l = lane & 15;
    int row0 = blockIdx.x * 128;
    f32x4 acc[4][4];
#pragma unroll
    for (int a = 0; a < 4; ++a)
#pragma unroll
        for (int b = 0; b < 4; ++b) acc[a][b] = (f32x4){0.f, 0.f, 0.f, 0.f};
#pragma unroll
    for (int it = 0; it < 8; ++it) {
        int cid = it * 128 + tid;
        int r = cid >> 3, kc = cid & 7;
        int gr = row0 + r;
        uint4 v = make_uint4(0, 0, 0, 0);
        if (gr < N_NODES) v = *(const uint4*)(T1 + (size_t)gr * HIDF + kc * 8);
        *(uint4*)&As[r * 72 + kc * 8] = v;
    }
#pragma unroll
    for (int it = 0; it < 4; ++it) {
        int cid = it * 128 + tid;
        int r = cid >> 3, kc = cid & 7;
        uint4 w = *(const uint4*)(w2t + (size_t)r * HIDF + kc * 8);
        *(uint4*)&Bs[r * 72 + kc * 8] = w;
    }
    __syncthreads();
#pragma unroll
    for (int ks = 0; ks < 64; ks += 32) {
        bf16x8 af[4], bfr[4];
#pragma unroll
        for (int mt = 0; mt < 4; ++mt)
            af[mt] = *(const bf16x8*)&As[(wave * 64 + mt * 16 + l) * 72 + ks + q * 8];
#pragma unroll
        for (int nt = 0; nt < 4; ++nt)
            bfr[nt] = *(const bf16x8*)&Bs[(nt * 16 + l) * 72 + ks + q * 8];
#pragma unroll
        for (int mt = 0; mt < 4; ++mt)
#pragma unroll
            for (int nt = 0; nt < 4; ++nt)
                acc[mt][nt] = __builtin_amdgcn_mfma_f32_16x16x32_bf16(
                    af[mt], bfr[nt], acc[mt][nt], 0, 0, 0);
    }
    float b2c[4];
#pragma unroll
    for (int nt = 0; nt < 4; ++nt) b2c[nt] = bf2f(canon[OFF_EB2 + nt * 16 + l]);
    __syncthreads();   // done reading As/Bs for MFMA
    // stage h0 tile in As (stride 72)
#pragma unroll
    for (int mt = 0; mt < 4; ++mt) {
#pragma unroll
        for (int r = 0; r < 4; ++r) {
            int lr = wave * 64 + mt * 16 + q * 4 + r;
#pragma unroll
            for (int nt = 0; nt < 4; ++nt)
                As[lr * 72 + nt * 16 + l] = f2bf(acc[mt][nt][r] + b2c[nt]);
        }
    }
    // stage p0 as floats in Bs region
    float* p0f = (float*)Bs;
    for (int i = tid; i < 512; i += 128) p0f[i] = bf2f(p0[i]);
    __syncthreads();
    // one thread per row: store h0 + compute 8 logits
    int row = tid, grow = row0 + row;
    if (grow < N_NODES) {
        const unsigned short* srow = &As[row * 72];
        unsigned short* hrow = h0 + (size_t)grow * HIDF;
#pragma unroll
        for (int i = 0; i < 8; ++i)
            *(uint4*)(hrow + i * 8) = *(const uint4*)(srow + i * 8);
        float s[8] = {};
#pragma unroll
        for (int k = 0; k < 64; ++k) {
            float hv = bf2f(srow[k]);
            const float* pp = &p0f[k * 8];
#pragma unroll
            for (int o = 0; o < 8; ++o) s[o] = fmaf(hv, pp[o], s[o]);
        }
#pragma unroll
        for (int h = 0; h < 4; ++h) {
            alS[(size_t)grow * 4 + h] = s[h];
            alD[(size_t)grow * 4 + h] = s[4 + h];
        }
    }
}

// ---------------- CSR build ----------------
__global__ void deg_init_k(int* __restrict__ deg) {
    int i = blockIdx.x * 256 + threadIdx.x;
    if (i < N_NODES) deg[i] = 1;
}
__global__ void deg_count_k(const int* __restrict__ dstI, int* __restrict__ deg) {
    int i = blockIdx.x * 256 + threadIdx.x;
    if (i < E_EDGES) atomicAdd(&deg[dstI[i]], 1);
}
__global__ __launch_bounds__(256) void scan1_k(const int* __restrict__ deg, int* __restrict__ excl,
                                               int* __restrict__ bsums) {
    int tid = threadIdx.x, lane = tid & 63, wv = tid >> 6;
    int gid = blockIdx.x * 256 + tid;
    int v = (gid < N_NODES) ? deg[gid] : 0;
    int inc = v;
#pragma unroll
    for (int off = 1; off < 64; off <<= 1) { int t = __shfl_up(inc, off); if (lane >= off) inc += t; }
    __shared__ int wsum[4];
    if (lane == 63) wsum[wv] = inc;
    __syncthreads();
    int wo = 0;
    for (int w = 0; w < wv; ++w) wo += wsum[w];
    int incl = inc + wo;
    if (gid < N_NODES) excl[gid] = incl - v;
    if (tid == 255) bsums[blockIdx.x] = incl;
}
__global__ __launch_bounds__(256) void scan2_k(const int* __restrict__ bsums, int* __restrict__ boff,
                                               int* __restrict__ totalp) {
    int tid = threadIdx.x, lane = tid & 63, wv = tid >> 6;
    int v = (tid < NB256) ? bsums[tid] : 0;
    int inc = v;
#pragma unroll
    for (int off = 1; off < 64; off <<= 1) { int t = __shfl_up(inc, off); if (lane >= off) inc += t; }
    __shared__ int wsum[4];
    if (lane == 63) wsum[wv] = inc;
    __syncthreads();
    int wo = 0;
    for (int w = 0; w < wv; ++w) wo += wsum[w];
    int incl = inc + wo;
    if (tid < NB256) boff[tid] = incl - v;
    if (tid == 255) *totalp = incl;
}
__global__ void scan3_k(const int* __restrict__ excl, const int* __restrict__ boff,
                        int* __restrict__ rowp, int* __restrict__ cursor) {
    int i = blockIdx.x * 256 + threadIdx.x;
    if (i < N_NODES) { int r = excl[i] + boff[i >> 8]; rowp[i] = r; cursor[i] = r; }
}
__global__ void fill_k(const int* __restrict__ srcI, const int* __restrict__ dstI,
                       int* __restrict__ cursor, int* __restrict__ colx) {
    int i = blockIdx.x * 256 + threadIdx.x;
    if (i >= E_EDGES + N_NODES) return;
    int s, d;
    if (i < E_EDGES) { s = srcI[i]; d = dstI[i]; } else { s = i - E_EDGES; d = s; }
    int slot = atomicAdd(&cursor[d], 1);
    colx[slot] = s;
}

// ---------------- layer-0 aggregate in 64-dim h0 space ----------------
__global__ __launch_bounds__(256) void agg0_k(
    const unsigned short* __restrict__ h0, const int* __restrict__ rowp, const int* __restrict__ colx,
    const float* __restrict__ alS, const float* __restrict__ alD,
    unsigned short* __restrict__ z0) {
    int tid = threadIdx.x, wave = tid >> 6, lane = tid & 63;
    int n = blockIdx.x * 4 + wave;
    if (n >= N_NODES) return;
    int start = rowp[n], end = rowp[n + 1];
    int e = lane >> 5;
    int c = lane & 31;
    int head = c >> 3;
    float adh = alD[(size_t)n * 4 + head];
    float a0 = 0.f, a1 = 0.f, asum = 0.f;
    int j = start;
    for (; j + 7 < end; j += 8) {
        int ja = j + e, jb = j + 2 + e, jc2 = j + 4 + e, jd = j + 6 + e;
        int sa = colx[ja], sb = colx[jb], sc = colx[jc2], sd = colx[jd];
        float ea = alS[(size_t)sa * 4 + head] + adh; ea = ea > 0.f ? ea : NEG * ea;
        float eb = alS[(size_t)sb * 4 + head] + adh; eb = eb > 0.f ? eb : NEG * eb;
        float ec = alS[(size_t)sc * 4 + head] + adh; ec = ec > 0.f ? ec : NEG * ec;
        float ed = alS[(size_t)sd * 4 + head] + adh; ed = ed > 0.f ? ed : NEG * ed;
        float wa = __expf(ea), wb = __expf(eb), wc = __expf(ec), wd = __expf(ed);
        unsigned int ua = *(const unsigned int*)(h0 + (size_t)sa * HIDF + c * 2);
        unsigned int ub = *(const unsigned int*)(h0 + (size_t)sb * HIDF + c * 2);
        unsigned int uc = *(const unsigned int*)(h0 + (size_t)sc * HIDF + c * 2);
        unsigned int ud = *(const unsigned int*)(h0 + (size_t)sd * HIDF + c * 2);
        asum += (wa + wb) + (wc + wd);
        a0 = fmaf(wa, bf2f((unsigned short)(ua & 0xffff)), a0);
        a1 = fmaf(wa, bf2f((unsigned short)(ua >> 16)),    a1);
        a0 = fmaf(wb, bf2f((unsigned short)(ub & 0xffff)), a0);
        a1 = fmaf(wb, bf2f((unsigned short)(ub >> 16)),    a1);
        a0 = fmaf(wc, bf2f((unsigned short)(uc & 0xffff)), a0);
        a1 = fmaf(wc, bf2f((unsigned short)(uc >> 16)),    a1);
        a0 = fmaf(wd, bf2f((unsigned short)(ud & 0xffff)), a0);
        a1 = fmaf(wd, bf2f((unsigned short)(ud >> 16)),    a1);
    }
    for (; j < end; j += 2) {
        int j1 = j + e;
        int jc = j1 < end ? j1 : end - 1;
        int s1 = colx[jc];
        float w1 = 0.f;
        if (j1 < end) {
            float ev = alS[(size_t)s1 * 4 + head] + adh;
            ev = ev > 0.f ? ev : NEG * ev;
            w1 = __expf(ev);
        }
        unsigned int u1 = *(const unsigned int*)(h0 + (size_t)s1 * HIDF + c * 2);
        asum += w1;
        a0 = fmaf(w1, bf2f((unsigned short)(u1 & 0xffff)), a0);
        a1 = fmaf(w1, bf2f((unsigned short)(u1 >> 16)),    a1);
    }
    a0 += __shfl_xor(a0, 32);
    a1 += __shfl_xor(a1, 32);
    asum += __shfl_xor(asum, 32);
    if (lane < 32) {
        float rh = 1.f / (asum + 1e-16f);
        unsigned int o = (unsigned int)f2bf(a0 * rh) | ((unsigned int)f2bf(a1 * rh) << 16);
        *(unsigned int*)(z0 + (size_t)n * HIDF + c * 2) = o;
    }
}

// ---------------- MFMA matmul; optional bias+ELU; optional fused logits ----------------
__global__ __launch_bounds__(256) void mfma_mm_k(
    const unsigned short* __restrict__ A, const unsigned short* __restrict__ Wt,
    unsigned short* __restrict__ C, int M, int K,
    const unsigned short* __restrict__ bias,
    const unsigned short* __restrict__ aSv, const unsigned short* __restrict__ aDv,
    float* __restrict__ alS, float* __restrict__ alD) {
    __shared__ unsigned short smem[128 * 72 * 2];   // As | Bs; reused as C-tile (128x136)
    unsigned short* As = smem;
    unsigned short* Bs = smem + 128 * 72;
    int tid = threadIdx.x;
    int wave = tid >> 6, lane = tid & 63;
    int wm = wave >> 1, wn = wave & 1;
    int row0 = blockIdx.y * 128, col0 = blockIdx.x * 128;
    int q = lane >> 4, l = lane & 15;
    f32x4 acc[4][4];
#pragma unroll
    for (int a = 0; a < 4; ++a)
#pragma unroll
        for (int b = 0; b < 4; ++b) acc[a][b] = (f32x4){0.f, 0.f, 0.f, 0.f};
    for (int kb = 0; kb < K; kb += 64) {
#pragma unroll
        for (int it = 0; it < 4; ++it) {
            int cid = it * 256 + tid;
            int r = cid >> 3, kc = cid & 7;
            int gr = row0 + r;
            uint4 v = make_uint4(0, 0, 0, 0);
            if (gr < M) v = *(const uint4*)(A + (size_t)gr * K + kb + kc * 8);
            *(uint4*)&As[r * 72 + kc * 8] = v;
            int gn = col0 + r;
            uint4 w = *(const uint4*)(Wt + (size_t)gn * K + kb + kc * 8);
            *(uint4*)&Bs[r * 72 + kc * 8] = w;
        }
        __syncthreads();
#pragma unroll
        for (int ks = 0; ks < 64; ks += 32) {
            bf16x8 af[4], bfr[4];
#pragma unroll
            for (int mt = 0; mt < 4; ++mt)
                af[mt] = *(const bf16x8*)&As[(wm * 64 + mt * 16 + l) * 72 + ks + q * 8];
#pragma unroll
            for (int nt = 0; nt < 4; ++nt)
                bfr[nt] = *(const bf16x8*)&Bs[(wn * 64 + nt * 16 + l) * 72 + ks + q * 8];
#pragma unroll
            for (int mt = 0; mt < 4; ++mt)
#pragma unroll
                for (int nt = 0; nt < 4; ++nt)
                    acc[mt][nt] = __builtin_amdgcn_mfma_f32_16x16x32_bf16(
                        af[mt], bfr[nt], acc[mt][nt], 0, 0, 0);
        }
        __syncthreads();
    }
    float bv[4] = {0.f, 0.f, 0.f, 0.f};
    bool doBias = (bias != nullptr);
    if (doBias) {
#pragma unroll
        for (int nt = 0; nt < 4; ++nt)
            bv[nt] = bf2f(bias[col0 + wn * 64 + nt * 16 + l]);
    }
#pragma unroll
    for (int mt = 0; mt < 4; ++mt) {
        int rowb = wm * 64 + mt * 16 + q * 4;
#pragma unroll
        for (int r = 0; r < 4; ++r) {
#pragma unroll
            for (int nt = 0; nt < 4; ++nt) {
                float v = acc[mt][nt][r];
                if (doBias) { v += bv[nt]; v = v > 0.f ? v : __expf(v) - 1.f; }
                smem[(rowb + r) * 136 + wn * 64 + nt * 16 + l] = f2bf(v);
            }
        }
    }
    __syncthreads();
    int row = tid >> 1, half = tid & 1;
    int grow = row0 + row;
    if (grow < M) {
        unsigned short* crow = C + (size_t)grow * D_F + col0 + half * 64;
        const unsigned short* srow = &smem[row * 136 + half * 64];
#pragma unroll
        for (int i = 0; i < 8; ++i)
            *(uint4*)(crow + i * 8) = *(const uint4*)(srow + i * 8);
        if (aSv != nullptr) {
            int head = (col0 >> 6) + half;
            const unsigned short* av = aSv + head * 64;
            const unsigned short* dv = aDv + head * 64;
            float ps = 0.f, pd = 0.f;
#pragma unroll
            for (int k = 0; k < 64; ++k) {
                float hv = bf2f(srow[k]);
                ps = fmaf(hv, bf2f(av[k]), ps);
                pd = fmaf(hv, bf2f(dv[k]), pd);
            }
            alS[(size_t)grow * 4 + head] = ps;
            alD[(size_t)grow * 4 + head] = pd;
        }
    }
}

// ---------------- fused GAT aggregate (256-dim): 16-edge unroll, denom on the fly ----------------
__global__ __launch_bounds__(256) void agg_k(
    const unsigned short* __restrict__ h2, const int* __restrict__ rowp, const int* __restrict__ colx,
    const float* __restrict__ alS, const float* __restrict__ alD,
    const unsigned short* __restrict__ bias, unsigned short* __restrict__ out) {
    int tid = threadIdx.x, wave = tid >> 6, lane = tid & 63;
    int n = blockIdx.x * 4 + wave;
    if (n >= N_NODES) return;
    int start = rowp[n], end = rowp[n + 1];
    int e = lane >> 5;
    int c = lane & 31;
    int head = c >> 3;
    float adh = alD[(size_t)n * 4 + head];
    float acc[8] = {};
    float asum = 0.f;
    int j = start;
    for (; j + 15 < end; j += 16) {     // 16 edges, 8 per parity, 8 loads in flight
        int ss[8];
#pragma unroll
        for (int t = 0; t < 8; ++t) ss[t] = colx[j + 2 * t + e];
        uint4 uu[8];
#pragma unroll
        for (int t = 0; t < 8; ++t) uu[t] = *(const uint4*)(h2 + (size_t)ss[t] * D_F + c * 8);
#pragma unroll
        for (int t = 0; t < 8; ++t) {
            float ev = alS[(size_t)ss[t] * 4 + head] + adh;
            ev = ev > 0.f ? ev : NEG * ev;
            float w = __expf(ev);
            asum += w;
            mac8(acc, w, uu[t]);
        }
    }
    for (; j + 3 < end; j += 4) {
        int s1 = colx[j + e], s2 = colx[j + 2 + e];
        uint4 u1 = *(const uint4*)(h2 + (size_t)s1 * D_F + c * 8);
        uint4 u2 = *(const uint4*)(h2 + (size_t)s2 * D_F + c * 8);
        float e1 = alS[(size_t)s1 * 4 + head] + adh; e1 = e1 > 0.f ? e1 : NEG * e1;
        float e2 = alS[(size_t)s2 * 4 + head] + adh; e2 = e2 > 0.f ? e2 : NEG * e2;
        float w1 = __expf(e1), w2 = __expf(e2);
        asum += w1 + w2;
        mac8(acc, w1, u1);
        mac8(acc, w2, u2);
    }
    for (; j < end; j += 2) {
        int j1 = j + e;
        int jc = j1 < end ? j1 : end - 1;
        int s1 = colx[jc];
        float w1 = 0.f;
        if (j1 < end) {
            float ev = alS[(size_t)s1 * 4 + head] + adh;
            ev = ev > 0.f ? ev : NEG * ev;
            w1 = __expf(ev);
        }
        uint4 u1 = *(const uint4*)(h2 + (size_t)s1 * D_F + c * 8);
        asum += w1;
        mac8(acc, w1, u1);
    }
#pragma unroll
    for (int k = 0; k < 8; ++k) acc[k] += __shfl_xor(acc[k], 32);
    asum += __shfl_xor(asum, 32);
    if (lane < 32) {
        float rh = 1.f / (asum + 1e-16f);
        uint4 bu = *(const uint4*)(bias + c * 8);
        float b[8];
        b[0] = bf2f((unsigned short)(bu.x & 0xffff)); b[1] = bf2f((unsigned short)(bu.x >> 16));
        b[2] = bf2f((unsigned short)(bu.y & 0xffff)); b[3] = bf2f((unsigned short)(bu.y >> 16));
        b[4] = bf2f((unsigned short)(bu.z & 0xffff)); b[5] = bf2f((unsigned short)(bu.z >> 16));
        b[6] = bf2f((unsigned short)(bu.w & 0xffff)); b[7] = bf2f((unsigned short)(bu.w >> 16));
        unsigned int o[4];
#pragma unroll
        for (int k = 0; k < 4; ++k) {
            float v0 = acc[2 * k] * rh + b[2 * k];
            float v1 = acc[2 * k + 1] * rh + b[2 * k + 1];
            v0 = v0 > 0.f ? v0 : __expf(v0) - 1.f;
            v1 = v1 > 0.f ? v1 : __expf(v1) - 1.f;
            o[k] = (unsigned int)f2bf(v0) | ((unsigned int)f2bf(v1) << 16);
        }
        *(uint4*)(out + (size_t)n * D_F + c * 8) = make_uint4(o[0], o[1], o[2], o[3]);
    }
}

// ---------------- pool ----------------
__global__ __launch_bounds__(256) void pool_k(const unsigned short* __restrict__ h,
                                              const int* __restrict__ batch,
                                              float* __restrict__ part, int* __restrict__ pcnt) {
    __shared__ float sums[GROUPS * D_F];
    __shared__ int cnts[GROUPS];
    int tid = threadIdx.x;
    for (int i = tid; i < GROUPS * D_F; i += 256) sums[i] = 0.f;
    if (tid < GROUPS) cnts[tid] = 0;
    __syncthreads();
    int n0 = blockIdx.x * POOL_CHUNK;
    int n1 = n0 + POOL_CHUNK; if (n1 > N_NODES) n1 = N_NODES;
    for (int n = n0; n < n1; ++n) {
        int b = batch[n];
        sums[b * D_F + tid] += bf2f(h[(size_t)n * D_F + tid]);
        if (tid == 0) cnts[b]++;
    }
    __syncthreads();
    float* po = part + (size_t)blockIdx.x * (GROUPS * D_F);
    for (int i = tid; i < GROUPS * D_F; i += 256) po[i] = sums[i];
    if (tid < GROUPS) pcnt[blockIdx.x * GROUPS + tid] = cnts[tid];
}

// ---------------- reduce ----------------
__global__ __launch_bounds__(256) void reduce_k(const float* __restrict__ part,
                                                const int* __restrict__ pcnt,
                                                float* __restrict__ gsum, int* __restrict__ gcnt) {
    int g = blockIdx.x, c = threadIdx.x;
    float s = 0.f;
    for (int b = 0; b < POOL_BLOCKS; ++b) s += part[(size_t)b * (GROUPS * D_F) + g * D_F + c];
    gsum[g * D_F + c] = s;
    if (threadIdx.x < 64) {
        int lane = threadIdx.x;
        int cn = 0;
        for (int b = lane; b < POOL_BLOCKS; b += 64) cn += pcnt[b * GROUPS + g];
#pragma unroll
        for (int off = 1; off < 64; off <<= 1) cn += __shfl_xor(cn, off);
        if (lane == 0) gcnt[g] = cn;
    }
}

// ---------------- decoder ----------------
__global__ __launch_bounds__(256) void dec_k(const float* __restrict__ gsum, const int* __restrict__ gcnt,
    const unsigned short* __restrict__ canon, const unsigned short* __restrict__ encg,
    void* __restrict__ outp) {
    const unsigned short* w1 = canon + OFF_DW1;
    const unsigned short* b1 = canon + OFF_DB1;
    const unsigned short* gam = canon + OFF_DG;
    const unsigned short* bet = canon + OFF_DBE;
    const unsigned short* w2 = canon + OFF_DW2;
    const unsigned short* b2 = canon + OFF_DB2;
    int tid = threadIdx.x, grp = blockIdx.x * 4 + (tid >> 6), lane = tid & 63;
    if (grp >= GROUPS) return;
    float inv = 1.0f / fmaxf((float)gcnt[grp], 1.0f);
    float p[4];
#pragma unroll
    for (int i = 0; i < 4; ++i) p[i] = gsum[grp * D_F + i * 64 + lane] * inv;
    float acc = bf2f(b1[lane]);
#pragma unroll
    for (int i = 0; i < 4; ++i)
        for (int k = 0; k < 64; ++k)
            acc = fmaf(__shfl(p[i], k), bf2f(w1[(i * 64 + k) * 64 + lane]), acc);
    float s = acc;
#pragma unroll
    for (int off = 32; off > 0; off >>= 1) s += __shfl_xor(s, off);
    float mean = s * (1.0f / 64.0f);
    float d = acc - mean;
    float vs = d * d;
#pragma unroll
    for (int off = 32; off > 0; off >>= 1) vs += __shfl_xor(vs, off);
    float rstd = rsqrtf(vs * (1.0f / 64.0f) + LNEPS);
    float val = bf2f(gam[lane]) * d * rstd + bf2f(bet[lane]);
    val = val > 0.f ? val : val * 0.f;
    int cl = (lane < OUT_F) ? lane : 0;
    float acc2 = 0.f;
    for (int k = 0; k < 64; ++k) {
        float wv = bf2f(w2[k * OUT_F + cl]);
        acc2 = fmaf(__shfl(val, k), wv, acc2);
    }
    if (lane < OUT_F) {
        float res = acc2 + bf2f(b2[lane]);
        if (dtype_flag(encg) == 0) ((unsigned short*)outp)[grp * OUT_F + lane] = f2bf(res);
        else                       ((float*)outp)[grp * OUT_F + lane] = res;
    }
}

extern "C" void kernel_launch(void* const* d_in, const int* in_sizes, int n_in,
                              void* d_out, int out_size, void* d_ws, size_t ws_size,
                              hipStream_t stream) {
    const int* ei    = (const int*)d_in[1];
    const int* batch = (const int*)d_in[2];

    char* p = (char*)d_ws;
    unsigned short* canon = (unsigned short*)p; p += (size_t)CANON_TOT * 2 + 16;
    unsigned short* bufA = (unsigned short*)p; p += (size_t)N_NODES * D_F * 2;
    unsigned short* bufB = (unsigned short*)p; p += (size_t)N_NODES * D_F * 2;
    unsigned short* zbuf = (unsigned short*)p; p += (size_t)N_NODES * HIDF * 2;
    unsigned short* wt0 = (unsigned short*)p; p += (size_t)64 * 256 * 2;
    unsigned short* wt1 = (unsigned short*)p; p += (size_t)256 * 256 * 2;
    unsigned short* wt2 = (unsigned short*)p; p += (size_t)256 * 256 * 2;
    unsigned short* w1t = (unsigned short*)p; p += (size_t)64 * 128 * 2;
    unsigned short* w2t = (unsigned short*)p; p += (size_t)64 * 64 * 2;
    unsigned short* p0  = (unsigned short*)p; p += (size_t)64 * 8 * 2 + 16;
    float* alS  = (float*)p; p += (size_t)N_NODES * 4 * 4;
    float* alD  = (float*)p; p += (size_t)N_NODES * 4 * 4;
    float* part = (float*)p; p += (size_t)POOL_BLOCKS * GROUPS * D_F * 4;
    int* pcnt   = (int*)p;   p += (size_t)POOL_BLOCKS * GROUPS * 4;
    float* gsum = (float*)p; p += GROUPS * D_F * 4;
    int* gcnt   = (int*)p;   p += 16 * 4;
    int* deg    = (int*)p;   p += (size_t)N_NODES * 4;
    int* excl   = (int*)p;   p += (size_t)N_NODES * 4;
    int* bsums  = (int*)p;   p += 256 * 4;
    int* boff   = (int*)p;   p += 256 * 4;
    int* rowp   = (int*)p;   p += (size_t)(N_NODES + 4) * 4;
    int* cursor = (int*)p;   p += (size_t)N_NODES * 4;
    int* colx   = (int*)p;   p += (size_t)(E_EDGES + N_NODES) * 4;

    const int* srcI = ei;
    const int* dstI = ei + E_EDGES;

    SP sp;
    sp.q[0] = d_in[0];
    for (int t = 1; t < 25; ++t) sp.q[t] = d_in[t + 2];

    int nwb = (N_NODES + 3) / 4;
    int nb128 = (N_NODES + 127) / 128;

    convert_k<<<(CANON_TOT + 255) / 256, 256, 0, stream>>>(sp, canon);
    wt_k<<<256, 256, 0, stream>>>(canon, wt0, wt1, wt2, w1t, w2t, p0);

    enc1_k<<<nb128, 128, 0, stream>>>(canon, w1t, bufB);
    enc2_k<<<nb128, 128, 0, stream>>>(canon, bufB, w2t, p0, bufA, alS, alD);  // bufA=h0 + logits

    deg_init_k<<<NB256, 256, 0, stream>>>(deg);
    deg_count_k<<<(E_EDGES + 255) / 256, 256, 0, stream>>>(dstI, deg);
    scan1_k<<<NB256, 256, 0, stream>>>(deg, excl, bsums);
    scan2_k<<<1, 256, 0, stream>>>(bsums, boff, rowp + N_NODES);
    scan3_k<<<NB256, 256, 0, stream>>>(excl, boff, rowp, cursor);
    fill_k<<<(E_EDGES + N_NODES + 255) / 256, 256, 0, stream>>>(srcI, dstI, cursor, colx);

    dim3 mmg(2, nb128);
    // layer 0 (swapped): aggregate h0 in 64-dim; then matmul w/ bias+ELU
    agg0_k<<<nwb, 256, 0, stream>>>(bufA, rowp, colx, alS, alD, zbuf);
    mfma_mm_k<<<mmg, 256, 0, stream>>>(zbuf, wt0, bufB, N_NODES, HIDF,
                                       canon + OFF_C0B, nullptr, nullptr, nullptr, nullptr);
    // layer 1
    mfma_mm_k<<<mmg, 256, 0, stream>>>(bufB, wt1, bufA, N_NODES, D_F,
                                       nullptr, canon + OFF_C1AS, canon + OFF_C1AD, alS, alD);
    agg_k<<<nwb, 256, 0, stream>>>(bufA, rowp, colx, alS, alD, canon + OFF_C1B, bufB);
    // layer 2
    mfma_mm_k<<<mmg, 256, 0, stream>>>(bufB, wt2, bufA, N_NODES, D_F,
                                       nullptr, canon + OFF_C2AS, canon + OFF_C2AD, alS, alD);
    agg_k<<<nwb, 256, 0, stream>>>(bufA, rowp, colx, alS, alD, canon + OFF_C2B, bufB);

    pool_k<<<POOL_BLOCKS, 256, 0, stream>>>(bufB, batch, part, pcnt);
    reduce_k<<<GROUPS, 256, 0, stream>>>(part, pcnt, gsum, gcnt);
    dec_k<<<2, 256, 0, stream>>>(gsum, gcnt, canon, (const unsigned short*)d_in[5], d_out);
}

// Round 13
// 595.300 us; speedup vs baseline: 1.0218x; 1.0218x over previous
//
#include <hip/hip_runtime.h>
#include <hip/hip_bf16.h>

#define N_NODES 50000
#define E_EDGES 800000
#define IN_F 128
#define HIDF 64
#define HEADS 4
#define OUT_F 40
#define GROUPS 8
#define D_F 256
#define NEG 0.2f
#define LNEPS 1e-5f
#define POOL_CHUNK 128
#define POOL_BLOCKS ((N_NODES + POOL_CHUNK - 1) / POOL_CHUNK)   // 391
#define NB256 ((N_NODES + 255) / 256)                            // 196

// canonical bf16 parameter buffer: element offsets
#define OFF_X    0
#define OFF_EW1  6400000
#define OFF_EB1  6408192
#define OFF_EG   6408256
#define OFF_EBE  6408320
#define OFF_EW2  6408384
#define OFF_EB2  6412480
#define OFF_C0W  6412544
#define OFF_C0AS 6428928
#define OFF_C0AD 6429184
#define OFF_C0B  6429440
#define OFF_C1W  6429696
#define OFF_C1AS 6495232
#define OFF_C1AD 6495488
#define OFF_C1B  6495744
#define OFF_C2W  6496000
#define OFF_C2AS 6561536
#define OFF_C2AD 6561792
#define OFF_C2B  6562048
#define OFF_DW1  6562304
#define OFF_DB1  6578688
#define OFF_DG   6578752
#define OFF_DBE  6578816
#define OFF_DW2  6578880
#define OFF_DB2  6581440
#define CANON_TOT 6581480

__device__ __constant__ int c_off[26] = {
    OFF_X, OFF_EW1, OFF_EB1, OFF_EG, OFF_EBE, OFF_EW2, OFF_EB2,
    OFF_C0W, OFF_C0AS, OFF_C0AD, OFF_C0B,
    OFF_C1W, OFF_C1AS, OFF_C1AD, OFF_C1B,
    OFF_C2W, OFF_C2AS, OFF_C2AD, OFF_C2B,
    OFF_DW1, OFF_DB1, OFF_DG, OFF_DBE, OFF_DW2, OFF_DB2, CANON_TOT};

typedef __attribute__((ext_vector_type(8))) short bf16x8;
typedef __attribute__((ext_vector_type(4))) float f32x4;

__device__ __forceinline__ float bf2f(unsigned short u) {
    union { unsigned int i; float f; } v; v.i = ((unsigned int)u) << 16; return v.f;
}
__device__ __forceinline__ unsigned short f2bf(float f) {
    union { float f; unsigned int i; } v; v.f = f;
    unsigned int r = v.i + 0x7FFF + ((v.i >> 16) & 1);   // RNE
    return (unsigned short)(r >> 16);
}
__device__ __forceinline__ void mac8(float* acc, float w, uint4 u) {
    acc[0] = fmaf(w, bf2f((unsigned short)(u.x & 0xffff)), acc[0]);
    acc[1] = fmaf(w, bf2f((unsigned short)(u.x >> 16)),    acc[1]);
    acc[2] = fmaf(w, bf2f((unsigned short)(u.y & 0xffff)), acc[2]);
    acc[3] = fmaf(w, bf2f((unsigned short)(u.y >> 16)),    acc[3]);
    acc[4] = fmaf(w, bf2f((unsigned short)(u.z & 0xffff)), acc[4]);
    acc[5] = fmaf(w, bf2f((unsigned short)(u.z >> 16)),    acc[5]);
    acc[6] = fmaf(w, bf2f((unsigned short)(u.w & 0xffff)), acc[6]);
    acc[7] = fmaf(w, bf2f((unsigned short)(u.w >> 16)),    acc[7]);
}
__device__ __forceinline__ int dtype_flag(const unsigned short* encg) {
    return (encg[0] == 0x0000 && encg[1] == 0x3F80) ? 1 : 0;
}

// ---------- canonicalize (flag computed inline; fast path for x) ----------
struct SP { const void* q[25]; };
__global__ __launch_bounds__(256) void convert_k(SP sp, unsigned short* __restrict__ canon) {
    int i = blockIdx.x * 256 + threadIdx.x;
    if (i >= CANON_TOT) return;
    int fl = dtype_flag((const unsigned short*)sp.q[3]);   // enc_g
    if (i < OFF_EW1) {
        canon[i] = fl == 0 ? ((const unsigned short*)sp.q[0])[i]
                           : f2bf(((const float*)sp.q[0])[i]);
        return;
    }
    int t = 1;
    while (i >= c_off[t + 1]) ++t;
    int j = i - c_off[t];
    const void* s = sp.q[t];
    canon[i] = fl == 0 ? ((const unsigned short*)s)[j] : f2bf(((const float*)s)[j]);
}

// ---------- weight transposes + layer-0 logit projection P0 = W0·a (64x8) ----------
__global__ void wt_k(const unsigned short* __restrict__ canon,
                     unsigned short* __restrict__ wt0, unsigned short* __restrict__ wt1,
                     unsigned short* __restrict__ wt2, unsigned short* __restrict__ w1t,
                     unsigned short* __restrict__ w2t, unsigned short* __restrict__ p0) {
    int i = blockIdx.x * 256 + threadIdx.x;   // 65536 threads
    if (i < 8192) {
        int k = i >> 6, n = i & 63;
        w1t[n * 128 + k] = canon[OFF_EW1 + k * 64 + n];
    }
    if (i < 4096) {
        int k = i >> 6, n = i & 63;
        w2t[n * 64 + k] = canon[OFF_EW2 + k * 64 + n];
    }
    if (i < 16384) {
        int k = i >> 8, n = i & 255;
        wt0[n * 64 + k] = canon[OFF_C0W + i];
    }
    if (i < 65536) {
        int k = i >> 8, n = i & 255;
        wt1[n * 256 + k] = canon[OFF_C1W + i];
        wt2[n * 256 + k] = canon[OFF_C2W + i];
    }
    if (i < 512) {   // P0[k][out], out = sd*4+h
        int out = i & 7, k = i >> 3;
        int h = out & 3, sd = out >> 2;
        int abase = (sd == 0 ? OFF_C0AS : OFF_C0AD) + h * 64;
        int wbase = OFF_C0W + k * 256 + h * 64;
        float s = 0.f;
        for (int c = 0; c < 64; ++c)
            s = fmaf(bf2f(canon[wbase + c]), bf2f(canon[abase + c]), s);
        p0[k * 8 + out] = f2bf(s);
    }
}

// ---------------- encoder stage 1: T1 = relu(LN(x@w1+b1)), MFMA + fused LN ----------------
__global__ __launch_bounds__(128) void enc1_k(const unsigned short* __restrict__ canon,
                                              const unsigned short* __restrict__ w1t,
                                              unsigned short* __restrict__ T1) {
    const unsigned short* x = canon + OFF_X;
    __shared__ unsigned short As[128 * 72];
    __shared__ unsigned short Bs[64 * 72];
    int tid = threadIdx.x, wave = tid >> 6, lane = tid & 63;
    int q = lane >> 4, l = lane & 15;
    int row0 = blockIdx.x * 128;
    f32x4 acc[4][4];
#pragma unroll
    for (int a = 0; a < 4; ++a)
#pragma unroll
        for (int b = 0; b < 4; ++b) acc[a][b] = (f32x4){0.f, 0.f, 0.f, 0.f};
    for (int kb = 0; kb < IN_F; kb += 64) {
#pragma unroll
        for (int it = 0; it < 8; ++it) {
            int cid = it * 128 + tid;
            int r = cid >> 3, kc = cid & 7;
            int gr = row0 + r;
            uint4 v = make_uint4(0, 0, 0, 0);
            if (gr < N_NODES) v = *(const uint4*)(x + (size_t)gr * IN_F + kb + kc * 8);
            *(uint4*)&As[r * 72 + kc * 8] = v;
        }
#pragma unroll
        for (int it = 0; it < 4; ++it) {
            int cid = it * 128 + tid;
            int r = cid >> 3, kc = cid & 7;
            uint4 w = *(const uint4*)(w1t + (size_t)r * IN_F + kb + kc * 8);
            *(uint4*)&Bs[r * 72 + kc * 8] = w;
        }
        __syncthreads();
#pragma unroll
        for (int ks = 0; ks < 64; ks += 32) {
            bf16x8 af[4], bfr[4];
#pragma unroll
            for (int mt = 0; mt < 4; ++mt)
                af[mt] = *(const bf16x8*)&As[(wave * 64 + mt * 16 + l) * 72 + ks + q * 8];
#pragma unroll
            for (int nt = 0; nt < 4; ++nt)
                bfr[nt] = *(const bf16x8*)&Bs[(nt * 16 + l) * 72 + ks + q * 8];
#pragma unroll
            for (int mt = 0; mt < 4; ++mt)
#pragma unroll
                for (int nt = 0; nt < 4; ++nt)
                    acc[mt][nt] = __builtin_amdgcn_mfma_f32_16x16x32_bf16(
                        af[mt], bfr[nt], acc[mt][nt], 0, 0, 0);
        }
        __syncthreads();
    }
    float b1c[4], gc[4], bec[4];
#pragma unroll
    for (int nt = 0; nt < 4; ++nt) {
        int c = nt * 16 + l;
        b1c[nt] = bf2f(canon[OFF_EB1 + c]);
        gc[nt]  = bf2f(canon[OFF_EG + c]);
        bec[nt] = bf2f(canon[OFF_EBE + c]);
    }
#pragma unroll
    for (int mt = 0; mt < 4; ++mt) {
#pragma unroll
        for (int r = 0; r < 4; ++r) {
            int grow = row0 + wave * 64 + mt * 16 + q * 4 + r;
            float v0 = acc[mt][0][r] + b1c[0];
            float v1 = acc[mt][1][r] + b1c[1];
            float v2 = acc[mt][2][r] + b1c[2];
            float v3 = acc[mt][3][r] + b1c[3];
            float s = v0 + v1 + v2 + v3;
#pragma unroll
            for (int off = 1; off < 16; off <<= 1) s += __shfl_xor(s, off);
            float mean = s * (1.0f / 64.0f);
            float d0 = v0 - mean, d1 = v1 - mean, d2 = v2 - mean, d3 = v3 - mean;
            float vs = d0 * d0 + d1 * d1 + d2 * d2 + d3 * d3;
#pragma unroll
            for (int off = 1; off < 16; off <<= 1) vs += __shfl_xor(vs, off);
            float rstd = rsqrtf(vs * (1.0f / 64.0f) + LNEPS);
            if (grow < N_NODES) {
                unsigned short* trow = T1 + (size_t)grow * HIDF;
                float o0 = gc[0] * d0 * rstd + bec[0]; o0 = fmaxf(o0, 0.f);
                float o1 = gc[1] * d1 * rstd + bec[1]; o1 = fmaxf(o1, 0.f);
                float o2 = gc[2] * d2 * rstd + bec[2]; o2 = fmaxf(o2, 0.f);
                float o3 = gc[3] * d3 * rstd + bec[3]; o3 = fmaxf(o3, 0.f);
                trow[l] = f2bf(o0); trow[16 + l] = f2bf(o1);
                trow[32 + l] = f2bf(o2); trow[48 + l] = f2bf(o3);
            }
        }
    }
}

// ---------------- encoder stage 2: h0 = T1 @ w2 + b2, fused layer-0 logits (1 thr/row) ----------------
__global__ __launch_bounds__(128) void enc2_k(const unsigned short* __restrict__ canon,
                                              const unsigned short* __restrict__ T1,
                                              const unsigned short* __restrict__ w2t,
                                              const unsigned short* __restrict__ p0,
                                              unsigned short* __restrict__ h0,
                                              float* __restrict__ alS, float* __restrict__ alD) {
    __shared__ unsigned short As[128 * 72];
    __shared__ unsigned short Bs[64 * 72];   // reused as float p0f[512] after MFMA
    int tid = threadIdx.x, wave = tid >> 6, lane = tid & 63;
    int q = lane >> 4, l = lane & 15;
    int row0 = blockIdx.x * 128;
    f32x4 acc[4][4];
#pragma unroll
    for (int a = 0; a < 4; ++a)
#pragma unroll
        for (int b = 0; b < 4; ++b) acc[a][b] = (f32x4){0.f, 0.f, 0.f, 0.f};
#pragma unroll
    for (int it = 0; it < 8; ++it) {
        int cid = it * 128 + tid;
        int r = cid >> 3, kc = cid & 7;
        int gr = row0 + r;
        uint4 v = make_uint4(0, 0, 0, 0);
        if (gr < N_NODES) v = *(const uint4*)(T1 + (size_t)gr * HIDF + kc * 8);
        *(uint4*)&As[r * 72 + kc * 8] = v;
    }
#pragma unroll
    for (int it = 0; it < 4; ++it) {
        int cid = it * 128 + tid;
        int r = cid >> 3, kc = cid & 7;
        uint4 w = *(const uint4*)(w2t + (size_t)r * HIDF + kc * 8);
        *(uint4*)&Bs[r * 72 + kc * 8] = w;
    }
    __syncthreads();
#pragma unroll
    for (int ks = 0; ks < 64; ks += 32) {
        bf16x8 af[4], bfr[4];
#pragma unroll
        for (int mt = 0; mt < 4; ++mt)
            af[mt] = *(const bf16x8*)&As[(wave * 64 + mt * 16 + l) * 72 + ks + q * 8];
#pragma unroll
        for (int nt = 0; nt < 4; ++nt)
            bfr[nt] = *(const bf16x8*)&Bs[(nt * 16 + l) * 72 + ks + q * 8];
#pragma unroll
        for (int mt = 0; mt < 4; ++mt)
#pragma unroll
            for (int nt = 0; nt < 4; ++nt)
                acc[mt][nt] = __builtin_amdgcn_mfma_f32_16x16x32_bf16(
                    af[mt], bfr[nt], acc[mt][nt], 0, 0, 0);
    }
    float b2c[4];
#pragma unroll
    for (int nt = 0; nt < 4; ++nt) b2c[nt] = bf2f(canon[OFF_EB2 + nt * 16 + l]);
    __syncthreads();   // done reading As/Bs for MFMA
    // stage h0 tile in As (stride 72)
#pragma unroll
    for (int mt = 0; mt < 4; ++mt) {
#pragma unroll
        for (int r = 0; r < 4; ++r) {
            int lr = wave * 64 + mt * 16 + q * 4 + r;
#pragma unroll
            for (int nt = 0; nt < 4; ++nt)
                As[lr * 72 + nt * 16 + l] = f2bf(acc[mt][nt][r] + b2c[nt]);
        }
    }
    float* p0f = (float*)Bs;
    for (int i = tid; i < 512; i += 128) p0f[i] = bf2f(p0[i]);
    __syncthreads();
    // one thread per row (128 threads = 128 rows): store h0 + compute 8 logits
    int row = tid, grow = row0 + row;
    if (grow < N_NODES) {
        const unsigned short* srow = &As[row * 72];
        unsigned short* hrow = h0 + (size_t)grow * HIDF;
#pragma unroll
        for (int i = 0; i < 8; ++i)
            *(uint4*)(hrow + i * 8) = *(const uint4*)(srow + i * 8);
        float s[8] = {};
#pragma unroll
        for (int k = 0; k < 64; ++k) {
            float hv = bf2f(srow[k]);
            const float* pp = &p0f[k * 8];
#pragma unroll
            for (int o = 0; o < 8; ++o) s[o] = fmaf(hv, pp[o], s[o]);
        }
#pragma unroll
        for (int h = 0; h < 4; ++h) {
            alS[(size_t)grow * 4 + h] = s[h];
            alD[(size_t)grow * 4 + h] = s[4 + h];
        }
    }
}

// ---------------- CSR build ----------------
__global__ void deg_init_k(int* __restrict__ deg) {
    int i = blockIdx.x * 256 + threadIdx.x;
    if (i < N_NODES) deg[i] = 1;
}
__global__ void deg_count_k(const int* __restrict__ dstI, int* __restrict__ deg) {
    int i = blockIdx.x * 256 + threadIdx.x;
    if (i < E_EDGES) atomicAdd(&deg[dstI[i]], 1);
}
__global__ __launch_bounds__(256) void scan1_k(const int* __restrict__ deg, int* __restrict__ excl,
                                               int* __restrict__ bsums) {
    int tid = threadIdx.x, lane = tid & 63, wv = tid >> 6;
    int gid = blockIdx.x * 256 + tid;
    int v = (gid < N_NODES) ? deg[gid] : 0;
    int inc = v;
#pragma unroll
    for (int off = 1; off < 64; off <<= 1) { int t = __shfl_up(inc, off); if (lane >= off) inc += t; }
    __shared__ int wsum[4];
    if (lane == 63) wsum[wv] = inc;
    __syncthreads();
    int wo = 0;
    for (int w = 0; w < wv; ++w) wo += wsum[w];
    int incl = inc + wo;
    if (gid < N_NODES) excl[gid] = incl - v;
    if (tid == 255) bsums[blockIdx.x] = incl;
}
__global__ __launch_bounds__(256) void scan2_k(const int* __restrict__ bsums, int* __restrict__ boff,
                                               int* __restrict__ totalp) {
    int tid = threadIdx.x, lane = tid & 63, wv = tid >> 6;
    int v = (tid < NB256) ? bsums[tid] : 0;
    int inc = v;
#pragma unroll
    for (int off = 1; off < 64; off <<= 1) { int t = __shfl_up(inc, off); if (lane >= off) inc += t; }
    __shared__ int wsum[4];
    if (lane == 63) wsum[wv] = inc;
    __syncthreads();
    int wo = 0;
    for (int w = 0; w < wv; ++w) wo += wsum[w];
    int incl = inc + wo;
    if (tid < NB256) boff[tid] = incl - v;
    if (tid == 255) *totalp = incl;
}
__global__ void scan3_k(const int* __restrict__ excl, const int* __restrict__ boff,
                        int* __restrict__ rowp, int* __restrict__ cursor) {
    int i = blockIdx.x * 256 + threadIdx.x;
    if (i < N_NODES) { int r = excl[i] + boff[i >> 8]; rowp[i] = r; cursor[i] = r; }
}
__global__ void fill_k(const int* __restrict__ srcI, const int* __restrict__ dstI,
                       int* __restrict__ cursor, int* __restrict__ colx) {
    int i = blockIdx.x * 256 + threadIdx.x;
    if (i >= E_EDGES + N_NODES) return;
    int s, d;
    if (i < E_EDGES) { s = srcI[i]; d = dstI[i]; } else { s = i - E_EDGES; d = s; }
    int slot = atomicAdd(&cursor[d], 1);
    colx[slot] = s;
}

// ---------------- layer-0 aggregate in 64-dim h0 space ----------------
__global__ __launch_bounds__(256) void agg0_k(
    const unsigned short* __restrict__ h0, const int* __restrict__ rowp, const int* __restrict__ colx,
    const float* __restrict__ alS, const float* __restrict__ alD,
    unsigned short* __restrict__ z0) {
    int tid = threadIdx.x, wave = tid >> 6, lane = tid & 63;
    int n = blockIdx.x * 4 + wave;
    if (n >= N_NODES) return;
    int start = rowp[n], end = rowp[n + 1];
    int e = lane >> 5;
    int c = lane & 31;
    int head = c >> 3;
    float adh = alD[(size_t)n * 4 + head];
    float a0 = 0.f, a1 = 0.f, asum = 0.f;
    int j = start;
    for (; j + 7 < end; j += 8) {
        int ja = j + e, jb = j + 2 + e, jc2 = j + 4 + e, jd = j + 6 + e;
        int sa = colx[ja], sb = colx[jb], sc = colx[jc2], sd = colx[jd];
        float ea = alS[(size_t)sa * 4 + head] + adh; ea = ea > 0.f ? ea : NEG * ea;
        float eb = alS[(size_t)sb * 4 + head] + adh; eb = eb > 0.f ? eb : NEG * eb;
        float ec = alS[(size_t)sc * 4 + head] + adh; ec = ec > 0.f ? ec : NEG * ec;
        float ed = alS[(size_t)sd * 4 + head] + adh; ed = ed > 0.f ? ed : NEG * ed;
        float wa = __expf(ea), wb = __expf(eb), wc = __expf(ec), wd = __expf(ed);
        unsigned int ua = *(const unsigned int*)(h0 + (size_t)sa * HIDF + c * 2);
        unsigned int ub = *(const unsigned int*)(h0 + (size_t)sb * HIDF + c * 2);
        unsigned int uc = *(const unsigned int*)(h0 + (size_t)sc * HIDF + c * 2);
        unsigned int ud = *(const unsigned int*)(h0 + (size_t)sd * HIDF + c * 2);
        asum += (wa + wb) + (wc + wd);
        a0 = fmaf(wa, bf2f((unsigned short)(ua & 0xffff)), a0);
        a1 = fmaf(wa, bf2f((unsigned short)(ua >> 16)),    a1);
        a0 = fmaf(wb, bf2f((unsigned short)(ub & 0xffff)), a0);
        a1 = fmaf(wb, bf2f((unsigned short)(ub >> 16)),    a1);
        a0 = fmaf(wc, bf2f((unsigned short)(uc & 0xffff)), a0);
        a1 = fmaf(wc, bf2f((unsigned short)(uc >> 16)),    a1);
        a0 = fmaf(wd, bf2f((unsigned short)(ud & 0xffff)), a0);
        a1 = fmaf(wd, bf2f((unsigned short)(ud >> 16)),    a1);
    }
    for (; j < end; j += 2) {
        int j1 = j + e;
        int jc = j1 < end ? j1 : end - 1;
        int s1 = colx[jc];
        float w1 = 0.f;
        if (j1 < end) {
            float ev = alS[(size_t)s1 * 4 + head] + adh;
            ev = ev > 0.f ? ev : NEG * ev;
            w1 = __expf(ev);
        }
        unsigned int u1 = *(const unsigned int*)(h0 + (size_t)s1 * HIDF + c * 2);
        asum += w1;
        a0 = fmaf(w1, bf2f((unsigned short)(u1 & 0xffff)), a0);
        a1 = fmaf(w1, bf2f((unsigned short)(u1 >> 16)),    a1);
    }
    a0 += __shfl_xor(a0, 32);
    a1 += __shfl_xor(a1, 32);
    asum += __shfl_xor(asum, 32);
    if (lane < 32) {
        float rh = 1.f / (asum + 1e-16f);
        unsigned int o = (unsigned int)f2bf(a0 * rh) | ((unsigned int)f2bf(a1 * rh) << 16);
        *(unsigned int*)(z0 + (size_t)n * HIDF + c * 2) = o;
    }
}

// ---------------- MFMA matmul; optional bias+ELU; optional fused logits ----------------
__global__ __launch_bounds__(256) void mfma_mm_k(
    const unsigned short* __restrict__ A, const unsigned short* __restrict__ Wt,
    unsigned short* __restrict__ C, int M, int K,
    const unsigned short* __restrict__ bias,
    const unsigned short* __restrict__ aSv, const unsigned short* __restrict__ aDv,
    float* __restrict__ alS, float* __restrict__ alD) {
    __shared__ unsigned short smem[128 * 72 * 2];   // As | Bs; reused as C-tile (128x136)
    unsigned short* As = smem;
    unsigned short* Bs = smem + 128 * 72;
    int tid = threadIdx.x;
    int wave = tid >> 6, lane = tid & 63;
    int wm = wave >> 1, wn = wave & 1;
    int row0 = blockIdx.y * 128, col0 = blockIdx.x * 128;
    int q = lane >> 4, l = lane & 15;
    f32x4 acc[4][4];
#pragma unroll
    for (int a = 0; a < 4; ++a)
#pragma unroll
        for (int b = 0; b < 4; ++b) acc[a][b] = (f32x4){0.f, 0.f, 0.f, 0.f};
    for (int kb = 0; kb < K; kb += 64) {
#pragma unroll
        for (int it = 0; it < 4; ++it) {
            int cid = it * 256 + tid;
            int r = cid >> 3, kc = cid & 7;
            int gr = row0 + r;
            uint4 v = make_uint4(0, 0, 0, 0);
            if (gr < M) v = *(const uint4*)(A + (size_t)gr * K + kb + kc * 8);
            *(uint4*)&As[r * 72 + kc * 8] = v;
            int gn = col0 + r;
            uint4 w = *(const uint4*)(Wt + (size_t)gn * K + kb + kc * 8);
            *(uint4*)&Bs[r * 72 + kc * 8] = w;
        }
        __syncthreads();
#pragma unroll
        for (int ks = 0; ks < 64; ks += 32) {
            bf16x8 af[4], bfr[4];
#pragma unroll
            for (int mt = 0; mt < 4; ++mt)
                af[mt] = *(const bf16x8*)&As[(wm * 64 + mt * 16 + l) * 72 + ks + q * 8];
#pragma unroll
            for (int nt = 0; nt < 4; ++nt)
                bfr[nt] = *(const bf16x8*)&Bs[(wn * 64 + nt * 16 + l) * 72 + ks + q * 8];
#pragma unroll
            for (int mt = 0; mt < 4; ++mt)
#pragma unroll
                for (int nt = 0; nt < 4; ++nt)
                    acc[mt][nt] = __builtin_amdgcn_mfma_f32_16x16x32_bf16(
                        af[mt], bfr[nt], acc[mt][nt], 0, 0, 0);
        }
        __syncthreads();
    }
    float bv[4] = {0.f, 0.f, 0.f, 0.f};
    bool doBias = (bias != nullptr);
    if (doBias) {
#pragma unroll
        for (int nt = 0; nt < 4; ++nt)
            bv[nt] = bf2f(bias[col0 + wn * 64 + nt * 16 + l]);
    }
#pragma unroll
    for (int mt = 0; mt < 4; ++mt) {
        int rowb = wm * 64 + mt * 16 + q * 4;
#pragma unroll
        for (int r = 0; r < 4; ++r) {
#pragma unroll
            for (int nt = 0; nt < 4; ++nt) {
                float v = acc[mt][nt][r];
                if (doBias) { v += bv[nt]; v = v > 0.f ? v : __expf(v) - 1.f; }
                smem[(rowb + r) * 136 + wn * 64 + nt * 16 + l] = f2bf(v);
            }
        }
    }
    __syncthreads();
    int row = tid >> 1, half = tid & 1;
    int grow = row0 + row;
    if (grow < M) {
        unsigned short* crow = C + (size_t)grow * D_F + col0 + half * 64;
        const unsigned short* srow = &smem[row * 136 + half * 64];
#pragma unroll
        for (int i = 0; i < 8; ++i)
            *(uint4*)(crow + i * 8) = *(const uint4*)(srow + i * 8);
        if (aSv != nullptr) {
            int head = (col0 >> 6) + half;
            const unsigned short* av = aSv + head * 64;
            const unsigned short* dv = aDv + head * 64;
            float ps = 0.f, pd = 0.f;
#pragma unroll
            for (int k = 0; k < 64; ++k) {
                float hv = bf2f(srow[k]);
                ps = fmaf(hv, bf2f(av[k]), ps);
                pd = fmaf(hv, bf2f(dv[k]), pd);
            }
            alS[(size_t)grow * 4 + head] = ps;
            alD[(size_t)grow * 4 + head] = pd;
        }
    }
}

// ---------------- fused GAT aggregate (256-dim): 8-edge loop, 4 loads in flight ----------------
__global__ __launch_bounds__(256) void agg_k(
    const unsigned short* __restrict__ h2, const int* __restrict__ rowp, const int* __restrict__ colx,
    const float* __restrict__ alS, const float* __restrict__ alD,
    const unsigned short* __restrict__ bias, unsigned short* __restrict__ out) {
    int tid = threadIdx.x, wave = tid >> 6, lane = tid & 63;
    int n = blockIdx.x * 4 + wave;
    if (n >= N_NODES) return;
    int start = rowp[n], end = rowp[n + 1];
    int e = lane >> 5;
    int c = lane & 31;
    int head = c >> 3;
    float adh = alD[(size_t)n * 4 + head];
    float acc[8] = {};
    float asum = 0.f;
    int j = start;
    for (; j + 7 < end; j += 8) {
        int ja = j + e, jb = j + 2 + e, jc2 = j + 4 + e, jd = j + 6 + e;
        int sa = colx[ja], sb = colx[jb], sc = colx[jc2], sd = colx[jd];
        float ea = alS[(size_t)sa * 4 + head] + adh; ea = ea > 0.f ? ea : NEG * ea;
        float eb = alS[(size_t)sb * 4 + head] + adh; eb = eb > 0.f ? eb : NEG * eb;
        float ec = alS[(size_t)sc * 4 + head] + adh; ec = ec > 0.f ? ec : NEG * ec;
        float ed = alS[(size_t)sd * 4 + head] + adh; ed = ed > 0.f ? ed : NEG * ed;
        float wa = __expf(ea), wb = __expf(eb), wc = __expf(ec), wd = __expf(ed);
        uint4 ua = *(const uint4*)(h2 + (size_t)sa * D_F + c * 8);
        uint4 ub = *(const uint4*)(h2 + (size_t)sb * D_F + c * 8);
        uint4 uc = *(const uint4*)(h2 + (size_t)sc * D_F + c * 8);
        uint4 ud = *(const uint4*)(h2 + (size_t)sd * D_F + c * 8);
        asum += (wa + wb) + (wc + wd);
        mac8(acc, wa, ua);
        mac8(acc, wb, ub);
        mac8(acc, wc, uc);
        mac8(acc, wd, ud);
    }
    for (; j < end; j += 2) {
        int j1 = j + e;
        int jc = j1 < end ? j1 : end - 1;
        int s1 = colx[jc];
        float w1 = 0.f;
        if (j1 < end) {
            float ev = alS[(size_t)s1 * 4 + head] + adh;
            ev = ev > 0.f ? ev : NEG * ev;
            w1 = __expf(ev);
        }
        uint4 u1 = *(const uint4*)(h2 + (size_t)s1 * D_F + c * 8);
        asum += w1;
        mac8(acc, w1, u1);
    }
#pragma unroll
    for (int k = 0; k < 8; ++k) acc[k] += __shfl_xor(acc[k], 32);
    asum += __shfl_xor(asum, 32);
    if (lane < 32) {
        float rh = 1.f / (asum + 1e-16f);
        uint4 bu = *(const uint4*)(bias + c * 8);
        float b[8];
        b[0] = bf2f((unsigned short)(bu.x & 0xffff)); b[1] = bf2f((unsigned short)(bu.x >> 16));
        b[2] = bf2f((unsigned short)(bu.y & 0xffff)); b[3] = bf2f((unsigned short)(bu.y >> 16));
        b[4] = bf2f((unsigned short)(bu.z & 0xffff)); b[5] = bf2f((unsigned short)(bu.z >> 16));
        b[6] = bf2f((unsigned short)(bu.w & 0xffff)); b[7] = bf2f((unsigned short)(bu.w >> 16));
        unsigned int o[4];
#pragma unroll
        for (int k = 0; k < 4; ++k) {
            float v0 = acc[2 * k] * rh + b[2 * k];
            float v1 = acc[2 * k + 1] * rh + b[2 * k + 1];
            v0 = v0 > 0.f ? v0 : __expf(v0) - 1.f;
            v1 = v1 > 0.f ? v1 : __expf(v1) - 1.f;
            o[k] = (unsigned int)f2bf(v0) | ((unsigned int)f2bf(v1) << 16);
        }
        *(uint4*)(out + (size_t)n * D_F + c * 8) = make_uint4(o[0], o[1], o[2], o[3]);
    }
}

// ---------------- pool ----------------
__global__ __launch_bounds__(256) void pool_k(const unsigned short* __restrict__ h,
                                              const int* __restrict__ batch,
                                              float* __restrict__ part, int* __restrict__ pcnt) {
    __shared__ float sums[GROUPS * D_F];
    __shared__ int cnts[GROUPS];
    int tid = threadIdx.x;
    for (int i = tid; i < GROUPS * D_F; i += 256) sums[i] = 0.f;
    if (tid < GROUPS) cnts[tid] = 0;
    __syncthreads();
    int n0 = blockIdx.x * POOL_CHUNK;
    int n1 = n0 + POOL_CHUNK; if (n1 > N_NODES) n1 = N_NODES;
    for (int n = n0; n < n1; ++n) {
        int b = batch[n];
        sums[b * D_F + tid] += bf2f(h[(size_t)n * D_F + tid]);
        if (tid == 0) cnts[b]++;
    }
    __syncthreads();
    float* po = part + (size_t)blockIdx.x * (GROUPS * D_F);
    for (int i = tid; i < GROUPS * D_F; i += 256) po[i] = sums[i];
    if (tid < GROUPS) pcnt[blockIdx.x * GROUPS + tid] = cnts[tid];
}

// ---------------- reduce ----------------
__global__ __launch_bounds__(256) void reduce_k(const float* __restrict__ part,
                                                const int* __restrict__ pcnt,
                                                float* __restrict__ gsum, int* __restrict__ gcnt) {
    int g = blockIdx.x, c = threadIdx.x;
    float s = 0.f;
    for (int b = 0; b < POOL_BLOCKS; ++b) s += part[(size_t)b * (GROUPS * D_F) + g * D_F + c];
    gsum[g * D_F + c] = s;
    if (threadIdx.x < 64) {
        int lane = threadIdx.x;
        int cn = 0;
        for (int b = lane; b < POOL_BLOCKS; b += 64) cn += pcnt[b * GROUPS + g];
#pragma unroll
        for (int off = 1; off < 64; off <<= 1) cn += __shfl_xor(cn, off);
        if (lane == 0) gcnt[g] = cn;
    }
}

// ---------------- decoder ----------------
__global__ __launch_bounds__(256) void dec_k(const float* __restrict__ gsum, const int* __restrict__ gcnt,
    const unsigned short* __restrict__ canon, const unsigned short* __restrict__ encg,
    void* __restrict__ outp) {
    const unsigned short* w1 = canon + OFF_DW1;
    const unsigned short* b1 = canon + OFF_DB1;
    const unsigned short* gam = canon + OFF_DG;
    const unsigned short* bet = canon + OFF_DBE;
    const unsigned short* w2 = canon + OFF_DW2;
    const unsigned short* b2 = canon + OFF_DB2;
    int tid = threadIdx.x, grp = blockIdx.x * 4 + (tid >> 6), lane = tid & 63;
    if (grp >= GROUPS) return;
    float inv = 1.0f / fmaxf((float)gcnt[grp], 1.0f);
    float p[4];
#pragma unroll
    for (int i = 0; i < 4; ++i) p[i] = gsum[grp * D_F + i * 64 + lane] * inv;
    float acc = bf2f(b1[lane]);
#pragma unroll
    for (int i = 0; i < 4; ++i)
        for (int k = 0; k < 64; ++k)
            acc = fmaf(__shfl(p[i], k), bf2f(w1[(i * 64 + k) * 64 + lane]), acc);
    float s = acc;
#pragma unroll
    for (int off = 32; off > 0; off >>= 1) s += __shfl_xor(s, off);
    float mean = s * (1.0f / 64.0f);
    float d = acc - mean;
    float vs = d * d;
#pragma unroll
    for (int off = 32; off > 0; off >>= 1) vs += __shfl_xor(vs, off);
    float rstd = rsqrtf(vs * (1.0f / 64.0f) + LNEPS);
    float val = bf2f(gam[lane]) * d * rstd + bf2f(bet[lane]);
    val = val > 0.f ? val : val * 0.f;
    int cl = (lane < OUT_F) ? lane : 0;
    float acc2 = 0.f;
    for (int k = 0; k < 64; ++k) {
        float wv = bf2f(w2[k * OUT_F + cl]);
        acc2 = fmaf(__shfl(val, k), wv, acc2);
    }
    if (lane < OUT_F) {
        float res = acc2 + bf2f(b2[lane]);
        if (dtype_flag(encg) == 0) ((unsigned short*)outp)[grp * OUT_F + lane] = f2bf(res);
        else                       ((float*)outp)[grp * OUT_F + lane] = res;
    }
}

extern "C" void kernel_launch(void* const* d_in, const int* in_sizes, int n_in,
                              void* d_out, int out_size, void* d_ws, size_t ws_size,
                              hipStream_t stream) {
    const int* ei    = (const int*)d_in[1];
    const int* batch = (const int*)d_in[2];

    char* p = (char*)d_ws;
    unsigned short* canon = (unsigned short*)p; p += (size_t)CANON_TOT * 2 + 16;
    unsigned short* bufA = (unsigned short*)p; p += (size_t)N_NODES * D_F * 2;
    unsigned short* bufB = (unsigned short*)p; p += (size_t)N_NODES * D_F * 2;
    unsigned short* zbuf = (unsigned short*)p; p += (size_t)N_NODES * HIDF * 2;
    unsigned short* wt0 = (unsigned short*)p; p += (size_t)64 * 256 * 2;
    unsigned short* wt1 = (unsigned short*)p; p += (size_t)256 * 256 * 2;
    unsigned short* wt2 = (unsigned short*)p; p += (size_t)256 * 256 * 2;
    unsigned short* w1t = (unsigned short*)p; p += (size_t)64 * 128 * 2;
    unsigned short* w2t = (unsigned short*)p; p += (size_t)64 * 64 * 2;
    unsigned short* p0  = (unsigned short*)p; p += (size_t)64 * 8 * 2 + 16;
    float* alS  = (float*)p; p += (size_t)N_NODES * 4 * 4;
    float* alD  = (float*)p; p += (size_t)N_NODES * 4 * 4;
    float* part = (float*)p; p += (size_t)POOL_BLOCKS * GROUPS * D_F * 4;
    int* pcnt   = (int*)p;   p += (size_t)POOL_BLOCKS * GROUPS * 4;
    float* gsum = (float*)p; p += GROUPS * D_F * 4;
    int* gcnt   = (int*)p;   p += 16 * 4;
    int* deg    = (int*)p;   p += (size_t)N_NODES * 4;
    int* excl   = (int*)p;   p += (size_t)N_NODES * 4;
    int* bsums  = (int*)p;   p += 256 * 4;
    int* boff   = (int*)p;   p += 256 * 4;
    int* rowp   = (int*)p;   p += (size_t)(N_NODES + 4) * 4;
    int* cursor = (int*)p;   p += (size_t)N_NODES * 4;
    int* colx   = (int*)p;   p += (size_t)(E_EDGES + N_NODES) * 4;

    const int* srcI = ei;
    const int* dstI = ei + E_EDGES;

    SP sp;
    sp.q[0] = d_in[0];
    for (int t = 1; t < 25; ++t) sp.q[t] = d_in[t + 2];

    int nwb = (N_NODES + 3) / 4;
    int nb128 = (N_NODES + 127) / 128;

    convert_k<<<(CANON_TOT + 255) / 256, 256, 0, stream>>>(sp, canon);
    wt_k<<<256, 256, 0, stream>>>(canon, wt0, wt1, wt2, w1t, w2t, p0);

    enc1_k<<<nb128, 128, 0, stream>>>(canon, w1t, bufB);
    enc2_k<<<nb128, 128, 0, stream>>>(canon, bufB, w2t, p0, bufA, alS, alD);  // bufA=h0 + logits

    deg_init_k<<<NB256, 256, 0, stream>>>(deg);
    deg_count_k<<<(E_EDGES + 255) / 256, 256, 0, stream>>>(dstI, deg);
    scan1_k<<<NB256, 256, 0, stream>>>(deg, excl, bsums);
    scan2_k<<<1, 256, 0, stream>>>(bsums, boff, rowp + N_NODES);
    scan3_k<<<NB256, 256, 0, stream>>>(excl, boff, rowp, cursor);
    fill_k<<<(E_EDGES + N_NODES + 255) / 256, 256, 0, stream>>>(srcI, dstI, cursor, colx);

    dim3 mmg(2, nb128);
    // layer 0 (swapped): aggregate h0 in 64-dim; then matmul w/ bias+ELU
    agg0_k<<<nwb, 256, 0, stream>>>(bufA, rowp, colx, alS, alD, zbuf);
    mfma_mm_k<<<mmg, 256, 0, stream>>>(zbuf, wt0, bufB, N_NODES, HIDF,
                                       canon + OFF_C0B, nullptr, nullptr, nullptr, nullptr);
    // layer 1
    mfma_mm_k<<<mmg, 256, 0, stream>>>(bufB, wt1, bufA, N_NODES, D_F,
                                       nullptr, canon + OFF_C1AS, canon + OFF_C1AD, alS, alD);
    agg_k<<<nwb, 256, 0, stream>>>(bufA, rowp, colx, alS, alD, canon + OFF_C1B, bufB);
    // layer 2
    mfma_mm_k<<<mmg, 256, 0, stream>>>(bufB, wt2, bufA, N_NODES, D_F,
                                       nullptr, canon + OFF_C2AS, canon + OFF_C2AD, alS, alD);
    agg_k<<<nwb, 256, 0, stream>>>(bufA, rowp, colx, alS, alD, canon + OFF_C2B, bufB);

    pool_k<<<POOL_BLOCKS, 256, 0, stream>>>(bufB, batch, part, pcnt);
    reduce_k<<<GROUPS, 256, 0, stream>>>(part, pcnt, gsum, gcnt);
    dec_k<<<2, 256, 0, stream>>>(gsum, gcnt, canon, (const unsigned short*)d_in[5], d_out);
}

// Round 14
// 575.868 us; speedup vs baseline: 1.0562x; 1.0337x over previous
//
#include <hip/hip_runtime.h>
#include <hip/hip_bf16.h>

#define N_NODES 50000
#define E_EDGES 800000
#define IN_F 128
#define HIDF 64
#define HEADS 4
#define OUT_F 40
#define GROUPS 8
#define D_F 256
#define NEG 0.2f
#define LNEPS 1e-5f
#define POOL_CHUNK 128
#define POOL_BLOCKS ((N_NODES + POOL_CHUNK - 1) / POOL_CHUNK)   // 391
#define NB256 ((N_NODES + 255) / 256)                            // 196

// canonical bf16 parameter buffer: element offsets
#define OFF_X    0
#define OFF_EW1  6400000
#define OFF_EB1  6408192
#define OFF_EG   6408256
#define OFF_EBE  6408320
#define OFF_EW2  6408384
#define OFF_EB2  6412480
#define OFF_C0W  6412544
#define OFF_C0AS 6428928
#define OFF_C0AD 6429184
#define OFF_C0B  6429440
#define OFF_C1W  6429696
#define OFF_C1AS 6495232
#define OFF_C1AD 6495488
#define OFF_C1B  6495744
#define OFF_C2W  6496000
#define OFF_C2AS 6561536
#define OFF_C2AD 6561792
#define OFF_C2B  6562048
#define OFF_DW1  6562304
#define OFF_DB1  6578688
#define OFF_DG   6578752
#define OFF_DBE  6578816
#define OFF_DW2  6578880
#define OFF_DB2  6581440
#define CANON_TOT 6581480
#define CONV_BLKS ((CANON_TOT + 255) / 256)                      // 25709

__device__ __constant__ int c_off[26] = {
    OFF_X, OFF_EW1, OFF_EB1, OFF_EG, OFF_EBE, OFF_EW2, OFF_EB2,
    OFF_C0W, OFF_C0AS, OFF_C0AD, OFF_C0B,
    OFF_C1W, OFF_C1AS, OFF_C1AD, OFF_C1B,
    OFF_C2W, OFF_C2AS, OFF_C2AD, OFF_C2B,
    OFF_DW1, OFF_DB1, OFF_DG, OFF_DBE, OFF_DW2, OFF_DB2, CANON_TOT};

typedef __attribute__((ext_vector_type(8))) short bf16x8;
typedef __attribute__((ext_vector_type(4))) float f32x4;

__device__ __forceinline__ float bf2f(unsigned short u) {
    union { unsigned int i; float f; } v; v.i = ((unsigned int)u) << 16; return v.f;
}
__device__ __forceinline__ unsigned short f2bf(float f) {
    union { float f; unsigned int i; } v; v.f = f;
    unsigned int r = v.i + 0x7FFF + ((v.i >> 16) & 1);   // RNE
    return (unsigned short)(r >> 16);
}
__device__ __forceinline__ void mac8(float* acc, float w, uint4 u) {
    acc[0] = fmaf(w, bf2f((unsigned short)(u.x & 0xffff)), acc[0]);
    acc[1] = fmaf(w, bf2f((unsigned short)(u.x >> 16)),    acc[1]);
    acc[2] = fmaf(w, bf2f((unsigned short)(u.y & 0xffff)), acc[2]);
    acc[3] = fmaf(w, bf2f((unsigned short)(u.y >> 16)),    acc[3]);
    acc[4] = fmaf(w, bf2f((unsigned short)(u.z & 0xffff)), acc[4]);
    acc[5] = fmaf(w, bf2f((unsigned short)(u.z >> 16)),    acc[5]);
    acc[6] = fmaf(w, bf2f((unsigned short)(u.w & 0xffff)), acc[6]);
    acc[7] = fmaf(w, bf2f((unsigned short)(u.w >> 16)),    acc[7]);
}
__device__ __forceinline__ int dtype_flag(const unsigned short* encg) {
    return (encg[0] == 0x0000 && encg[1] == 0x3F80) ? 1 : 0;
}

// ---------- canonicalize + deg_init (extra blocks) ----------
struct SP { const void* q[25]; };
__global__ __launch_bounds__(256) void convert_k(SP sp, unsigned short* __restrict__ canon,
                                                 int* __restrict__ deg) {
    if (blockIdx.x >= CONV_BLKS) {
        int i = (blockIdx.x - CONV_BLKS) * 256 + threadIdx.x;
        if (i < N_NODES) deg[i] = 1;   // self-loop
        return;
    }
    int i = blockIdx.x * 256 + threadIdx.x;
    if (i >= CANON_TOT) return;
    int fl = dtype_flag((const unsigned short*)sp.q[3]);   // enc_g
    if (i < OFF_EW1) {
        canon[i] = fl == 0 ? ((const unsigned short*)sp.q[0])[i]
                           : f2bf(((const float*)sp.q[0])[i]);
        return;
    }
    int t = 1;
    while (i >= c_off[t + 1]) ++t;
    int j = i - c_off[t];
    const void* s = sp.q[t];
    canon[i] = fl == 0 ? ((const unsigned short*)s)[j] : f2bf(((const float*)s)[j]);
}

// ---------- weight transposes + layer-0 logit projection P0 = W0·a (64x8) ----------
__global__ void wt_k(const unsigned short* __restrict__ canon,
                     unsigned short* __restrict__ wt0, unsigned short* __restrict__ wt1,
                     unsigned short* __restrict__ wt2, unsigned short* __restrict__ w1t,
                     unsigned short* __restrict__ w2t, unsigned short* __restrict__ p0) {
    int i = blockIdx.x * 256 + threadIdx.x;   // 65536 threads
    if (i < 8192) {
        int k = i >> 6, n = i & 63;
        w1t[n * 128 + k] = canon[OFF_EW1 + k * 64 + n];
    }
    if (i < 4096) {
        int k = i >> 6, n = i & 63;
        w2t[n * 64 + k] = canon[OFF_EW2 + k * 64 + n];
    }
    if (i < 16384) {
        int k = i >> 8, n = i & 255;
        wt0[n * 64 + k] = canon[OFF_C0W + i];
    }
    if (i < 65536) {
        int k = i >> 8, n = i & 255;
        wt1[n * 256 + k] = canon[OFF_C1W + i];
        wt2[n * 256 + k] = canon[OFF_C2W + i];
    }
    if (i < 512) {   // P0[k][out], out = sd*4+h
        int out = i & 7, k = i >> 3;
        int h = out & 3, sd = out >> 2;
        int abase = (sd == 0 ? OFF_C0AS : OFF_C0AD) + h * 64;
        int wbase = OFF_C0W + k * 256 + h * 64;
        float s = 0.f;
        for (int c = 0; c < 64; ++c)
            s = fmaf(bf2f(canon[wbase + c]), bf2f(canon[abase + c]), s);
        p0[k * 8 + out] = f2bf(s);
    }
}

// ---------------- fused encoder: h0 = relu(LN(x@w1+b1))@w2+b2, T1 kept in LDS; fused l0 logits ----------------
__global__ __launch_bounds__(128) void enc_k(const unsigned short* __restrict__ canon,
                                             const unsigned short* __restrict__ w1t,
                                             const unsigned short* __restrict__ w2t,
                                             const unsigned short* __restrict__ p0,
                                             unsigned short* __restrict__ h0,
                                             float* __restrict__ alS, float* __restrict__ alD) {
    const unsigned short* x = canon + OFF_X;
    __shared__ unsigned short As[128 * 72];
    __shared__ unsigned short Bs[64 * 72];
    int tid = threadIdx.x, wave = tid >> 6, lane = tid & 63;
    int q = lane >> 4, l = lane & 15;
    int row0 = blockIdx.x * 128;
    // ---- GEMM1: T1pre = x @ w1 ----
    f32x4 acc[4][4];
#pragma unroll
    for (int a = 0; a < 4; ++a)
#pragma unroll
        for (int b = 0; b < 4; ++b) acc[a][b] = (f32x4){0.f, 0.f, 0.f, 0.f};
    for (int kb = 0; kb < IN_F; kb += 64) {
#pragma unroll
        for (int it = 0; it < 8; ++it) {
            int cid = it * 128 + tid;
            int r = cid >> 3, kc = cid & 7;
            int gr = row0 + r;
            uint4 v = make_uint4(0, 0, 0, 0);
            if (gr < N_NODES) v = *(const uint4*)(x + (size_t)gr * IN_F + kb + kc * 8);
            *(uint4*)&As[r * 72 + kc * 8] = v;
        }
#pragma unroll
        for (int it = 0; it < 4; ++it) {
            int cid = it * 128 + tid;
            int r = cid >> 3, kc = cid & 7;
            uint4 w = *(const uint4*)(w1t + (size_t)r * IN_F + kb + kc * 8);
            *(uint4*)&Bs[r * 72 + kc * 8] = w;
        }
        __syncthreads();
#pragma unroll
        for (int ks = 0; ks < 64; ks += 32) {
            bf16x8 af[4], bfr[4];
#pragma unroll
            for (int mt = 0; mt < 4; ++mt)
                af[mt] = *(const bf16x8*)&As[(wave * 64 + mt * 16 + l) * 72 + ks + q * 8];
#pragma unroll
            for (int nt = 0; nt < 4; ++nt)
                bfr[nt] = *(const bf16x8*)&Bs[(nt * 16 + l) * 72 + ks + q * 8];
#pragma unroll
            for (int mt = 0; mt < 4; ++mt)
#pragma unroll
                for (int nt = 0; nt < 4; ++nt)
                    acc[mt][nt] = __builtin_amdgcn_mfma_f32_16x16x32_bf16(
                        af[mt], bfr[nt], acc[mt][nt], 0, 0, 0);
        }
        __syncthreads();
    }
    // ---- epilogue1: bias + LN + relu -> T1 tile into As (stride 72) ----
    float b1c[4], gc[4], bec[4];
#pragma unroll
    for (int nt = 0; nt < 4; ++nt) {
        int c = nt * 16 + l;
        b1c[nt] = bf2f(canon[OFF_EB1 + c]);
        gc[nt]  = bf2f(canon[OFF_EG + c]);
        bec[nt] = bf2f(canon[OFF_EBE + c]);
    }
#pragma unroll
    for (int mt = 0; mt < 4; ++mt) {
#pragma unroll
        for (int r = 0; r < 4; ++r) {
            int lr = wave * 64 + mt * 16 + q * 4 + r;
            float v0 = acc[mt][0][r] + b1c[0];
            float v1 = acc[mt][1][r] + b1c[1];
            float v2 = acc[mt][2][r] + b1c[2];
            float v3 = acc[mt][3][r] + b1c[3];
            float s = v0 + v1 + v2 + v3;
#pragma unroll
            for (int off = 1; off < 16; off <<= 1) s += __shfl_xor(s, off);
            float mean = s * (1.0f / 64.0f);
            float d0 = v0 - mean, d1 = v1 - mean, d2 = v2 - mean, d3 = v3 - mean;
            float vs = d0 * d0 + d1 * d1 + d2 * d2 + d3 * d3;
#pragma unroll
            for (int off = 1; off < 16; off <<= 1) vs += __shfl_xor(vs, off);
            float rstd = rsqrtf(vs * (1.0f / 64.0f) + LNEPS);
            float o0 = gc[0] * d0 * rstd + bec[0]; o0 = fmaxf(o0, 0.f);
            float o1 = gc[1] * d1 * rstd + bec[1]; o1 = fmaxf(o1, 0.f);
            float o2 = gc[2] * d2 * rstd + bec[2]; o2 = fmaxf(o2, 0.f);
            float o3 = gc[3] * d3 * rstd + bec[3]; o3 = fmaxf(o3, 0.f);
            As[lr * 72 + l] = f2bf(o0);
            As[lr * 72 + 16 + l] = f2bf(o1);
            As[lr * 72 + 32 + l] = f2bf(o2);
            As[lr * 72 + 48 + l] = f2bf(o3);
        }
    }
    // ---- stage w2t into Bs ----
#pragma unroll
    for (int it = 0; it < 4; ++it) {
        int cid = it * 128 + tid;
        int r = cid >> 3, kc = cid & 7;
        uint4 w = *(const uint4*)(w2t + (size_t)r * HIDF + kc * 8);
        *(uint4*)&Bs[r * 72 + kc * 8] = w;
    }
    __syncthreads();
    // ---- GEMM2: h0 = T1 @ w2 ----
    f32x4 acc2[4][4];
#pragma unroll
    for (int a = 0; a < 4; ++a)
#pragma unroll
        for (int b = 0; b < 4; ++b) acc2[a][b] = (f32x4){0.f, 0.f, 0.f, 0.f};
#pragma unroll
    for (int ks = 0; ks < 64; ks += 32) {
        bf16x8 af[4], bfr[4];
#pragma unroll
        for (int mt = 0; mt < 4; ++mt)
            af[mt] = *(const bf16x8*)&As[(wave * 64 + mt * 16 + l) * 72 + ks + q * 8];
#pragma unroll
        for (int nt = 0; nt < 4; ++nt)
            bfr[nt] = *(const bf16x8*)&Bs[(nt * 16 + l) * 72 + ks + q * 8];
#pragma unroll
        for (int mt = 0; mt < 4; ++mt)
#pragma unroll
            for (int nt = 0; nt < 4; ++nt)
                acc2[mt][nt] = __builtin_amdgcn_mfma_f32_16x16x32_bf16(
                    af[mt], bfr[nt], acc2[mt][nt], 0, 0, 0);
    }
    float b2c[4];
#pragma unroll
    for (int nt = 0; nt < 4; ++nt) b2c[nt] = bf2f(canon[OFF_EB2 + nt * 16 + l]);
    __syncthreads();   // done reading As(T1)/Bs(w2t)
    // ---- stage h0 tile into As, p0 floats into Bs ----
#pragma unroll
    for (int mt = 0; mt < 4; ++mt) {
#pragma unroll
        for (int r = 0; r < 4; ++r) {
            int lr = wave * 64 + mt * 16 + q * 4 + r;
#pragma unroll
            for (int nt = 0; nt < 4; ++nt)
                As[lr * 72 + nt * 16 + l] = f2bf(acc2[mt][nt][r] + b2c[nt]);
        }
    }
    float* p0f = (float*)Bs;
    for (int i = tid; i < 512; i += 128) p0f[i] = bf2f(p0[i]);
    __syncthreads();
    // ---- one thread per row: store h0 + 8 logits ----
    int row = tid, grow = row0 + row;
    if (grow < N_NODES) {
        const unsigned short* srow = &As[row * 72];
        unsigned short* hrow = h0 + (size_t)grow * HIDF;
#pragma unroll
        for (int i = 0; i < 8; ++i)
            *(uint4*)(hrow + i * 8) = *(const uint4*)(srow + i * 8);
        float s[8] = {};
#pragma unroll
        for (int k = 0; k < 64; ++k) {
            float hv = bf2f(srow[k]);
            const float* pp = &p0f[k * 8];
#pragma unroll
            for (int o = 0; o < 8; ++o) s[o] = fmaf(hv, pp[o], s[o]);
        }
#pragma unroll
        for (int h = 0; h < 4; ++h) {
            alS[(size_t)grow * 4 + h] = s[h];
            alD[(size_t)grow * 4 + h] = s[4 + h];
        }
    }
}

// ---------------- CSR build ----------------
__global__ void deg_count_k(const int* __restrict__ dstI, int* __restrict__ deg) {
    int i = blockIdx.x * 256 + threadIdx.x;
    if (i < E_EDGES) atomicAdd(&deg[dstI[i]], 1);
}
__global__ __launch_bounds__(256) void scan1_k(const int* __restrict__ deg, int* __restrict__ excl,
                                               int* __restrict__ bsums) {
    int tid = threadIdx.x, lane = tid & 63, wv = tid >> 6;
    int gid = blockIdx.x * 256 + tid;
    int v = (gid < N_NODES) ? deg[gid] : 0;
    int inc = v;
#pragma unroll
    for (int off = 1; off < 64; off <<= 1) { int t = __shfl_up(inc, off); if (lane >= off) inc += t; }
    __shared__ int wsum[4];
    if (lane == 63) wsum[wv] = inc;
    __syncthreads();
    int wo = 0;
    for (int w = 0; w < wv; ++w) wo += wsum[w];
    int incl = inc + wo;
    if (gid < N_NODES) excl[gid] = incl - v;
    if (tid == 255) bsums[blockIdx.x] = incl;
}
__global__ __launch_bounds__(256) void scan2_k(const int* __restrict__ bsums, int* __restrict__ boff,
                                               int* __restrict__ totalp) {
    int tid = threadIdx.x, lane = tid & 63, wv = tid >> 6;
    int v = (tid < NB256) ? bsums[tid] : 0;
    int inc = v;
#pragma unroll
    for (int off = 1; off < 64; off <<= 1) { int t = __shfl_up(inc, off); if (lane >= off) inc += t; }
    __shared__ int wsum[4];
    if (lane == 63) wsum[wv] = inc;
    __syncthreads();
    int wo = 0;
    for (int w = 0; w < wv; ++w) wo += wsum[w];
    int incl = inc + wo;
    if (tid < NB256) boff[tid] = incl - v;
    if (tid == 255) *totalp = incl;
}
__global__ void scan3_k(const int* __restrict__ excl, const int* __restrict__ boff,
                        int* __restrict__ rowp, int* __restrict__ cursor) {
    int i = blockIdx.x * 256 + threadIdx.x;
    if (i < N_NODES) { int r = excl[i] + boff[i >> 8]; rowp[i] = r; cursor[i] = r; }
}
__global__ void fill_k(const int* __restrict__ srcI, const int* __restrict__ dstI,
                       int* __restrict__ cursor, int* __restrict__ colx) {
    int i = blockIdx.x * 256 + threadIdx.x;
    if (i >= E_EDGES + N_NODES) return;
    int s, d;
    if (i < E_EDGES) { s = srcI[i]; d = dstI[i]; } else { s = i - E_EDGES; d = s; }
    int slot = atomicAdd(&cursor[d], 1);
    colx[slot] = s;
}

// ---------------- layer-0 aggregate in 64-dim h0 space ----------------
__global__ __launch_bounds__(256) void agg0_k(
    const unsigned short* __restrict__ h0, const int* __restrict__ rowp, const int* __restrict__ colx,
    const float* __restrict__ alS, const float* __restrict__ alD,
    unsigned short* __restrict__ z0) {
    int tid = threadIdx.x, wave = tid >> 6, lane = tid & 63;
    int n = blockIdx.x * 4 + wave;
    if (n >= N_NODES) return;
    int start = rowp[n], end = rowp[n + 1];
    int e = lane >> 5;
    int c = lane & 31;
    int head = c >> 3;
    float adh = alD[(size_t)n * 4 + head];
    float a0 = 0.f, a1 = 0.f, asum = 0.f;
    int j = start;
    for (; j + 7 < end; j += 8) {
        int ja = j + e, jb = j + 2 + e, jc2 = j + 4 + e, jd = j + 6 + e;
        int sa = colx[ja], sb = colx[jb], sc = colx[jc2], sd = colx[jd];
        float ea = alS[(size_t)sa * 4 + head] + adh; ea = ea > 0.f ? ea : NEG * ea;
        float eb = alS[(size_t)sb * 4 + head] + adh; eb = eb > 0.f ? eb : NEG * eb;
        float ec = alS[(size_t)sc * 4 + head] + adh; ec = ec > 0.f ? ec : NEG * ec;
        float ed = alS[(size_t)sd * 4 + head] + adh; ed = ed > 0.f ? ed : NEG * ed;
        float wa = __expf(ea), wb = __expf(eb), wc = __expf(ec), wd = __expf(ed);
        unsigned int ua = *(const unsigned int*)(h0 + (size_t)sa * HIDF + c * 2);
        unsigned int ub = *(const unsigned int*)(h0 + (size_t)sb * HIDF + c * 2);
        unsigned int uc = *(const unsigned int*)(h0 + (size_t)sc * HIDF + c * 2);
        unsigned int ud = *(const unsigned int*)(h0 + (size_t)sd * HIDF + c * 2);
        asum += (wa + wb) + (wc + wd);
        a0 = fmaf(wa, bf2f((unsigned short)(ua & 0xffff)), a0);
        a1 = fmaf(wa, bf2f((unsigned short)(ua >> 16)),    a1);
        a0 = fmaf(wb, bf2f((unsigned short)(ub & 0xffff)), a0);
        a1 = fmaf(wb, bf2f((unsigned short)(ub >> 16)),    a1);
        a0 = fmaf(wc, bf2f((unsigned short)(uc & 0xffff)), a0);
        a1 = fmaf(wc, bf2f((unsigned short)(uc >> 16)),    a1);
        a0 = fmaf(wd, bf2f((unsigned short)(ud & 0xffff)), a0);
        a1 = fmaf(wd, bf2f((unsigned short)(ud >> 16)),    a1);
    }
    for (; j < end; j += 2) {
        int j1 = j + e;
        int jc = j1 < end ? j1 : end - 1;
        int s1 = colx[jc];
        float w1 = 0.f;
        if (j1 < end) {
            float ev = alS[(size_t)s1 * 4 + head] + adh;
            ev = ev > 0.f ? ev : NEG * ev;
            w1 = __expf(ev);
        }
        unsigned int u1 = *(const unsigned int*)(h0 + (size_t)s1 * HIDF + c * 2);
        asum += w1;
        a0 = fmaf(w1, bf2f((unsigned short)(u1 & 0xffff)), a0);
        a1 = fmaf(w1, bf2f((unsigned short)(u1 >> 16)),    a1);
    }
    a0 += __shfl_xor(a0, 32);
    a1 += __shfl_xor(a1, 32);
    asum += __shfl_xor(asum, 32);
    if (lane < 32) {
        float rh = 1.f / (asum + 1e-16f);
        unsigned int o = (unsigned int)f2bf(a0 * rh) | ((unsigned int)f2bf(a1 * rh) << 16);
        *(unsigned int*)(z0 + (size_t)n * HIDF + c * 2) = o;
    }
}

// ---------------- MFMA matmul; optional bias+ELU; optional fused logits ----------------
__global__ __launch_bounds__(256) void mfma_mm_k(
    const unsigned short* __restrict__ A, const unsigned short* __restrict__ Wt,
    unsigned short* __restrict__ C, int M, int K,
    const unsigned short* __restrict__ bias,
    const unsigned short* __restrict__ aSv, const unsigned short* __restrict__ aDv,
    float* __restrict__ alS, float* __restrict__ alD) {
    __shared__ unsigned short smem[128 * 72 * 2];   // As | Bs; reused as C-tile (128x136)
    unsigned short* As = smem;
    unsigned short* Bs = smem + 128 * 72;
    int tid = threadIdx.x;
    int wave = tid >> 6, lane = tid & 63;
    int wm = wave >> 1, wn = wave & 1;
    int row0 = blockIdx.y * 128, col0 = blockIdx.x * 128;
    int q = lane >> 4, l = lane & 15;
    f32x4 acc[4][4];
#pragma unroll
    for (int a = 0; a < 4; ++a)
#pragma unroll
        for (int b = 0; b < 4; ++b) acc[a][b] = (f32x4){0.f, 0.f, 0.f, 0.f};
    for (int kb = 0; kb < K; kb += 64) {
#pragma unroll
        for (int it = 0; it < 4; ++it) {
            int cid = it * 256 + tid;
            int r = cid >> 3, kc = cid & 7;
            int gr = row0 + r;
            uint4 v = make_uint4(0, 0, 0, 0);
            if (gr < M) v = *(const uint4*)(A + (size_t)gr * K + kb + kc * 8);
            *(uint4*)&As[r * 72 + kc * 8] = v;
            int gn = col0 + r;
            uint4 w = *(const uint4*)(Wt + (size_t)gn * K + kb + kc * 8);
            *(uint4*)&Bs[r * 72 + kc * 8] = w;
        }
        __syncthreads();
#pragma unroll
        for (int ks = 0; ks < 64; ks += 32) {
            bf16x8 af[4], bfr[4];
#pragma unroll
            for (int mt = 0; mt < 4; ++mt)
                af[mt] = *(const bf16x8*)&As[(wm * 64 + mt * 16 + l) * 72 + ks + q * 8];
#pragma unroll
            for (int nt = 0; nt < 4; ++nt)
                bfr[nt] = *(const bf16x8*)&Bs[(wn * 64 + nt * 16 + l) * 72 + ks + q * 8];
#pragma unroll
            for (int mt = 0; mt < 4; ++mt)
#pragma unroll
                for (int nt = 0; nt < 4; ++nt)
                    acc[mt][nt] = __builtin_amdgcn_mfma_f32_16x16x32_bf16(
                        af[mt], bfr[nt], acc[mt][nt], 0, 0, 0);
        }
        __syncthreads();
    }
    float bv[4] = {0.f, 0.f, 0.f, 0.f};
    bool doBias = (bias != nullptr);
    if (doBias) {
#pragma unroll
        for (int nt = 0; nt < 4; ++nt)
            bv[nt] = bf2f(bias[col0 + wn * 64 + nt * 16 + l]);
    }
#pragma unroll
    for (int mt = 0; mt < 4; ++mt) {
        int rowb = wm * 64 + mt * 16 + q * 4;
#pragma unroll
        for (int r = 0; r < 4; ++r) {
#pragma unroll
            for (int nt = 0; nt < 4; ++nt) {
                float v = acc[mt][nt][r];
                if (doBias) { v += bv[nt]; v = v > 0.f ? v : __expf(v) - 1.f; }
                smem[(rowb + r) * 136 + wn * 64 + nt * 16 + l] = f2bf(v);
            }
        }
    }
    __syncthreads();
    int row = tid >> 1, half = tid & 1;
    int grow = row0 + row;
    if (grow < M) {
        unsigned short* crow = C + (size_t)grow * D_F + col0 + half * 64;
        const unsigned short* srow = &smem[row * 136 + half * 64];
#pragma unroll
        for (int i = 0; i < 8; ++i)
            *(uint4*)(crow + i * 8) = *(const uint4*)(srow + i * 8);
        if (aSv != nullptr) {
            int head = (col0 >> 6) + half;
            const unsigned short* av = aSv + head * 64;
            const unsigned short* dv = aDv + head * 64;
            float ps = 0.f, pd = 0.f;
#pragma unroll
            for (int k = 0; k < 64; ++k) {
                float hv = bf2f(srow[k]);
                ps = fmaf(hv, bf2f(av[k]), ps);
                pd = fmaf(hv, bf2f(dv[k]), pd);
            }
            alS[(size_t)grow * 4 + head] = ps;
            alD[(size_t)grow * 4 + head] = pd;
        }
    }
}

// ---------------- fused GAT aggregate (256-dim): 8-edge loop, 4 loads in flight ----------------
__global__ __launch_bounds__(256) void agg_k(
    const unsigned short* __restrict__ h2, const int* __restrict__ rowp, const int* __restrict__ colx,
    const float* __restrict__ alS, const float* __restrict__ alD,
    const unsigned short* __restrict__ bias, unsigned short* __restrict__ out) {
    int tid = threadIdx.x, wave = tid >> 6, lane = tid & 63;
    int n = blockIdx.x * 4 + wave;
    if (n >= N_NODES) return;
    int start = rowp[n], end = rowp[n + 1];
    int e = lane >> 5;
    int c = lane & 31;
    int head = c >> 3;
    float adh = alD[(size_t)n * 4 + head];
    float acc[8] = {};
    float asum = 0.f;
    int j = start;
    for (; j + 7 < end; j += 8) {
        int ja = j + e, jb = j + 2 + e, jc2 = j + 4 + e, jd = j + 6 + e;
        int sa = colx[ja], sb = colx[jb], sc = colx[jc2], sd = colx[jd];
        float ea = alS[(size_t)sa * 4 + head] + adh; ea = ea > 0.f ? ea : NEG * ea;
        float eb = alS[(size_t)sb * 4 + head] + adh; eb = eb > 0.f ? eb : NEG * eb;
        float ec = alS[(size_t)sc * 4 + head] + adh; ec = ec > 0.f ? ec : NEG * ec;
        float ed = alS[(size_t)sd * 4 + head] + adh; ed = ed > 0.f ? ed : NEG * ed;
        float wa = __expf(ea), wb = __expf(eb), wc = __expf(ec), wd = __expf(ed);
        uint4 ua = *(const uint4*)(h2 + (size_t)sa * D_F + c * 8);
        uint4 ub = *(const uint4*)(h2 + (size_t)sb * D_F + c * 8);
        uint4 uc = *(const uint4*)(h2 + (size_t)sc * D_F + c * 8);
        uint4 ud = *(const uint4*)(h2 + (size_t)sd * D_F + c * 8);
        asum += (wa + wb) + (wc + wd);
        mac8(acc, wa, ua);
        mac8(acc, wb, ub);
        mac8(acc, wc, uc);
        mac8(acc, wd, ud);
    }
    for (; j < end; j += 2) {
        int j1 = j + e;
        int jc = j1 < end ? j1 : end - 1;
        int s1 = colx[jc];
        float w1 = 0.f;
        if (j1 < end) {
            float ev = alS[(size_t)s1 * 4 + head] + adh;
            ev = ev > 0.f ? ev : NEG * ev;
            w1 = __expf(ev);
        }
        uint4 u1 = *(const uint4*)(h2 + (size_t)s1 * D_F + c * 8);
        asum += w1;
        mac8(acc, w1, u1);
    }
#pragma unroll
    for (int k = 0; k < 8; ++k) acc[k] += __shfl_xor(acc[k], 32);
    asum += __shfl_xor(asum, 32);
    if (lane < 32) {
        float rh = 1.f / (asum + 1e-16f);
        uint4 bu = *(const uint4*)(bias + c * 8);
        float b[8];
        b[0] = bf2f((unsigned short)(bu.x & 0xffff)); b[1] = bf2f((unsigned short)(bu.x >> 16));
        b[2] = bf2f((unsigned short)(bu.y & 0xffff)); b[3] = bf2f((unsigned short)(bu.y >> 16));
        b[4] = bf2f((unsigned short)(bu.z & 0xffff)); b[5] = bf2f((unsigned short)(bu.z >> 16));
        b[6] = bf2f((unsigned short)(bu.w & 0xffff)); b[7] = bf2f((unsigned short)(bu.w >> 16));
        unsigned int o[4];
#pragma unroll
        for (int k = 0; k < 4; ++k) {
            float v0 = acc[2 * k] * rh + b[2 * k];
            float v1 = acc[2 * k + 1] * rh + b[2 * k + 1];
            v0 = v0 > 0.f ? v0 : __expf(v0) - 1.f;
            v1 = v1 > 0.f ? v1 : __expf(v1) - 1.f;
            o[k] = (unsigned int)f2bf(v0) | ((unsigned int)f2bf(v1) << 16);
        }
        *(uint4*)(out + (size_t)n * D_F + c * 8) = make_uint4(o[0], o[1], o[2], o[3]);
    }
}

// ---------------- pool: batch sorted -> register accumulation, flush on group change ----------------
__global__ __launch_bounds__(256) void pool_k(const unsigned short* __restrict__ h,
                                              const int* __restrict__ batch,
                                              float* __restrict__ part, int* __restrict__ pcnt) {
    __shared__ float sums[GROUPS * D_F];
    __shared__ int cnts[GROUPS];
    int tid = threadIdx.x, wave = tid >> 6, lane = tid & 63;
    for (int i = tid; i < GROUPS * D_F; i += 256) sums[i] = 0.f;
    if (tid < GROUPS) cnts[tid] = 0;
    __syncthreads();
    // wave handles a contiguous 32-node stripe; lane covers channels lane*4..lane*4+3
    int n0 = blockIdx.x * POOL_CHUNK + wave * (POOL_CHUNK / 4);
    int n1 = n0 + POOL_CHUNK / 4; if (n1 > N_NODES) n1 = N_NODES;
    float a0 = 0.f, a1 = 0.f, a2 = 0.f, a3 = 0.f;
    int curb = -1, cnt = 0;
    for (int n = n0; n < n1; ++n) {
        int b = batch[n];
        if (b != curb) {
            if (curb >= 0) {
                atomicAdd(&sums[curb * D_F + lane * 4 + 0], a0);
                atomicAdd(&sums[curb * D_F + lane * 4 + 1], a1);
                atomicAdd(&sums[curb * D_F + lane * 4 + 2], a2);
                atomicAdd(&sums[curb * D_F + lane * 4 + 3], a3);
                if (lane == 0) atomicAdd(&cnts[curb], cnt);
            }
            a0 = a1 = a2 = a3 = 0.f; cnt = 0; curb = b;
        }
        uint2 u = *(const uint2*)(h + (size_t)n * D_F + lane * 4);
        a0 += bf2f((unsigned short)(u.x & 0xffff));
        a1 += bf2f((unsigned short)(u.x >> 16));
        a2 += bf2f((unsigned short)(u.y & 0xffff));
        a3 += bf2f((unsigned short)(u.y >> 16));
        ++cnt;
    }
    if (curb >= 0) {
        atomicAdd(&sums[curb * D_F + lane * 4 + 0], a0);
        atomicAdd(&sums[curb * D_F + lane * 4 + 1], a1);
        atomicAdd(&sums[curb * D_F + lane * 4 + 2], a2);
        atomicAdd(&sums[curb * D_F + lane * 4 + 3], a3);
        if (lane == 0) atomicAdd(&cnts[curb], cnt);
    }
    __syncthreads();
    float* po = part + (size_t)blockIdx.x * (GROUPS * D_F);
    for (int i = tid; i < GROUPS * D_F; i += 256) po[i] = sums[i];
    if (tid < GROUPS) pcnt[blockIdx.x * GROUPS + tid] = cnts[tid];
}

// ---------------- reduce ----------------
__global__ __launch_bounds__(256) void reduce_k(const float* __restrict__ part,
                                                const int* __restrict__ pcnt,
                                                float* __restrict__ gsum, int* __restrict__ gcnt) {
    int g = blockIdx.x, c = threadIdx.x;
    float s = 0.f;
    for (int b = 0; b < POOL_BLOCKS; ++b) s += part[(size_t)b * (GROUPS * D_F) + g * D_F + c];
    gsum[g * D_F + c] = s;
    if (threadIdx.x < 64) {
        int lane = threadIdx.x;
        int cn = 0;
        for (int b = lane; b < POOL_BLOCKS; b += 64) cn += pcnt[b * GROUPS + g];
#pragma unroll
        for (int off = 1; off < 64; off <<= 1) cn += __shfl_xor(cn, off);
        if (lane == 0) gcnt[g] = cn;
    }
}

// ---------------- decoder ----------------
__global__ __launch_bounds__(256) void dec_k(const float* __restrict__ gsum, const int* __restrict__ gcnt,
    const unsigned short* __restrict__ canon, const unsigned short* __restrict__ encg,
    void* __restrict__ outp) {
    const unsigned short* w1 = canon + OFF_DW1;
    const unsigned short* b1 = canon + OFF_DB1;
    const unsigned short* gam = canon + OFF_DG;
    const unsigned short* bet = canon + OFF_DBE;
    const unsigned short* w2 = canon + OFF_DW2;
    const unsigned short* b2 = canon + OFF_DB2;
    int tid = threadIdx.x, grp = blockIdx.x * 4 + (tid >> 6), lane = tid & 63;
    if (grp >= GROUPS) return;
    float inv = 1.0f / fmaxf((float)gcnt[grp], 1.0f);
    float p[4];
#pragma unroll
    for (int i = 0; i < 4; ++i) p[i] = gsum[grp * D_F + i * 64 + lane] * inv;
    float acc = bf2f(b1[lane]);
#pragma unroll
    for (int i = 0; i < 4; ++i)
        for (int k = 0; k < 64; ++k)
            acc = fmaf(__shfl(p[i], k), bf2f(w1[(i * 64 + k) * 64 + lane]), acc);
    float s = acc;
#pragma unroll
    for (int off = 32; off > 0; off >>= 1) s += __shfl_xor(s, off);
    float mean = s * (1.0f / 64.0f);
    float d = acc - mean;
    float vs = d * d;
#pragma unroll
    for (int off = 32; off > 0; off >>= 1) vs += __shfl_xor(vs, off);
    float rstd = rsqrtf(vs * (1.0f / 64.0f) + LNEPS);
    float val = bf2f(gam[lane]) * d * rstd + bf2f(bet[lane]);
    val = val > 0.f ? val : val * 0.f;
    int cl = (lane < OUT_F) ? lane : 0;
    float acc2 = 0.f;
    for (int k = 0; k < 64; ++k) {
        float wv = bf2f(w2[k * OUT_F + cl]);
        acc2 = fmaf(__shfl(val, k), wv, acc2);
    }
    if (lane < OUT_F) {
        float res = acc2 + bf2f(b2[lane]);
        if (dtype_flag(encg) == 0) ((unsigned short*)outp)[grp * OUT_F + lane] = f2bf(res);
        else                       ((float*)outp)[grp * OUT_F + lane] = res;
    }
}

extern "C" void kernel_launch(void* const* d_in, const int* in_sizes, int n_in,
                              void* d_out, int out_size, void* d_ws, size_t ws_size,
                              hipStream_t stream) {
    const int* ei    = (const int*)d_in[1];
    const int* batch = (const int*)d_in[2];

    char* p = (char*)d_ws;
    unsigned short* canon = (unsigned short*)p; p += (size_t)CANON_TOT * 2 + 16;
    unsigned short* bufA = (unsigned short*)p; p += (size_t)N_NODES * D_F * 2;
    unsigned short* bufB = (unsigned short*)p; p += (size_t)N_NODES * D_F * 2;
    unsigned short* zbuf = (unsigned short*)p; p += (size_t)N_NODES * HIDF * 2;
    unsigned short* wt0 = (unsigned short*)p; p += (size_t)64 * 256 * 2;
    unsigned short* wt1 = (unsigned short*)p; p += (size_t)256 * 256 * 2;
    unsigned short* wt2 = (unsigned short*)p; p += (size_t)256 * 256 * 2;
    unsigned short* w1t = (unsigned short*)p; p += (size_t)64 * 128 * 2;
    unsigned short* w2t = (unsigned short*)p; p += (size_t)64 * 64 * 2;
    unsigned short* p0  = (unsigned short*)p; p += (size_t)64 * 8 * 2 + 16;
    float* alS  = (float*)p; p += (size_t)N_NODES * 4 * 4;
    float* alD  = (float*)p; p += (size_t)N_NODES * 4 * 4;
    float* part = (float*)p; p += (size_t)POOL_BLOCKS * GROUPS * D_F * 4;
    int* pcnt   = (int*)p;   p += (size_t)POOL_BLOCKS * GROUPS * 4;
    float* gsum = (float*)p; p += GROUPS * D_F * 4;
    int* gcnt   = (int*)p;   p += 16 * 4;
    int* deg    = (int*)p;   p += (size_t)N_NODES * 4;
    int* excl   = (int*)p;   p += (size_t)N_NODES * 4;
    int* bsums  = (int*)p;   p += 256 * 4;
    int* boff   = (int*)p;   p += 256 * 4;
    int* rowp   = (int*)p;   p += (size_t)(N_NODES + 4) * 4;
    int* cursor = (int*)p;   p += (size_t)N_NODES * 4;
    int* colx   = (int*)p;   p += (size_t)(E_EDGES + N_NODES) * 4;

    const int* srcI = ei;
    const int* dstI = ei + E_EDGES;

    SP sp;
    sp.q[0] = d_in[0];
    for (int t = 1; t < 25; ++t) sp.q[t] = d_in[t + 2];

    int nwb = (N_NODES + 3) / 4;
    int nb128 = (N_NODES + 127) / 128;

    convert_k<<<CONV_BLKS + NB256, 256, 0, stream>>>(sp, canon, deg);   // + deg_init
    wt_k<<<256, 256, 0, stream>>>(canon, wt0, wt1, wt2, w1t, w2t, p0);
    deg_count_k<<<(E_EDGES + 255) / 256, 256, 0, stream>>>(dstI, deg);

    enc_k<<<nb128, 128, 0, stream>>>(canon, w1t, w2t, p0, bufA, alS, alD);  // bufA=h0 + logits

    scan1_k<<<NB256, 256, 0, stream>>>(deg, excl, bsums);
    scan2_k<<<1, 256, 0, stream>>>(bsums, boff, rowp + N_NODES);
    scan3_k<<<NB256, 256, 0, stream>>>(excl, boff, rowp, cursor);
    fill_k<<<(E_EDGES + N_NODES + 255) / 256, 256, 0, stream>>>(srcI, dstI, cursor, colx);

    dim3 mmg(2, nb128);
    // layer 0 (swapped): aggregate h0 in 64-dim; then matmul w/ bias+ELU
    agg0_k<<<nwb, 256, 0, stream>>>(bufA, rowp, colx, alS, alD, zbuf);
    mfma_mm_k<<<mmg, 256, 0, stream>>>(zbuf, wt0, bufB, N_NODES, HIDF,
                                       canon + OFF_C0B, nullptr, nullptr, nullptr, nullptr);
    // layer 1
    mfma_mm_k<<<mmg, 256, 0, stream>>>(bufB, wt1, bufA, N_NODES, D_F,
                                       nullptr, canon + OFF_C1AS, canon + OFF_C1AD, alS, alD);
    agg_k<<<nwb, 256, 0, stream>>>(bufA, rowp, colx, alS, alD, canon + OFF_C1B, bufB);
    // layer 2
    mfma_mm_k<<<mmg, 256, 0, stream>>>(bufB, wt2, bufA, N_NODES, D_F,
                                       nullptr, canon + OFF_C2AS, canon + OFF_C2AD, alS, alD);
    agg_k<<<nwb, 256, 0, stream>>>(bufA, rowp, colx, alS, alD, canon + OFF_C2B, bufB);

    pool_k<<<POOL_BLOCKS, 256, 0, stream>>>(bufB, batch, part, pcnt);
    reduce_k<<<GROUPS, 256, 0, stream>>>(part, pcnt, gsum, gcnt);
    dec_k<<<2, 256, 0, stream>>>(gsum, gcnt, canon, (const unsigned short*)d_in[5], d_out);
}

// Round 15
// 557.543 us; speedup vs baseline: 1.0910x; 1.0329x over previous
//
#include <hip/hip_runtime.h>
#include <hip/hip_bf16.h>

#define N_NODES 50000
#define E_EDGES 800000
#define IN_F 128
#define HIDF 64
#define HEADS 4
#define OUT_F 40
#define GROUPS 8
#define D_F 256
#define NEG 0.2f
#define LNEPS 1e-5f
#define POOL_CHUNK 128
#define POOL_BLOCKS ((N_NODES + POOL_CHUNK - 1) / POOL_CHUNK)   // 391
#define NB256 ((N_NODES + 255) / 256)                            // 196

// canonical bf16 parameter buffer: element offsets (x no longer canonicalized)
#define OFF_X    0
#define OFF_EW1  6400000
#define OFF_EB1  6408192
#define OFF_EG   6408256
#define OFF_EBE  6408320
#define OFF_EW2  6408384
#define OFF_EB2  6412480
#define OFF_C0W  6412544
#define OFF_C0AS 6428928
#define OFF_C0AD 6429184
#define OFF_C0B  6429440
#define OFF_C1W  6429696
#define OFF_C1AS 6495232
#define OFF_C1AD 6495488
#define OFF_C1B  6495744
#define OFF_C2W  6496000
#define OFF_C2AS 6561536
#define OFF_C2AD 6561792
#define OFF_C2B  6562048
#define OFF_DW1  6562304
#define OFF_DB1  6578688
#define OFF_DG   6578752
#define OFF_DBE  6578816
#define OFF_DW2  6578880
#define OFF_DB2  6581440
#define CANON_TOT 6581480
#define CONV_W_BLKS ((CANON_TOT - OFF_EW1 + 255) / 256)          // 709 (weights only)

__device__ __constant__ int c_off[26] = {
    OFF_X, OFF_EW1, OFF_EB1, OFF_EG, OFF_EBE, OFF_EW2, OFF_EB2,
    OFF_C0W, OFF_C0AS, OFF_C0AD, OFF_C0B,
    OFF_C1W, OFF_C1AS, OFF_C1AD, OFF_C1B,
    OFF_C2W, OFF_C2AS, OFF_C2AD, OFF_C2B,
    OFF_DW1, OFF_DB1, OFF_DG, OFF_DBE, OFF_DW2, OFF_DB2, CANON_TOT};

typedef __attribute__((ext_vector_type(8))) short bf16x8;
typedef __attribute__((ext_vector_type(4))) float f32x4;

__device__ __forceinline__ float bf2f(unsigned short u) {
    union { unsigned int i; float f; } v; v.i = ((unsigned int)u) << 16; return v.f;
}
__device__ __forceinline__ unsigned short f2bf(float f) {
    union { float f; unsigned int i; } v; v.f = f;
    unsigned int r = v.i + 0x7FFF + ((v.i >> 16) & 1);   // RNE
    return (unsigned short)(r >> 16);
}
__device__ __forceinline__ void mac8(float* acc, float w, uint4 u) {
    acc[0] = fmaf(w, bf2f((unsigned short)(u.x & 0xffff)), acc[0]);
    acc[1] = fmaf(w, bf2f((unsigned short)(u.x >> 16)),    acc[1]);
    acc[2] = fmaf(w, bf2f((unsigned short)(u.y & 0xffff)), acc[2]);
    acc[3] = fmaf(w, bf2f((unsigned short)(u.y >> 16)),    acc[3]);
    acc[4] = fmaf(w, bf2f((unsigned short)(u.z & 0xffff)), acc[4]);
    acc[5] = fmaf(w, bf2f((unsigned short)(u.z >> 16)),    acc[5]);
    acc[6] = fmaf(w, bf2f((unsigned short)(u.w & 0xffff)), acc[6]);
    acc[7] = fmaf(w, bf2f((unsigned short)(u.w >> 16)),    acc[7]);
}
__device__ __forceinline__ int dtype_flag(const unsigned short* encg) {
    return (encg[0] == 0x0000 && encg[1] == 0x3F80) ? 1 : 0;
}
__device__ __forceinline__ unsigned int pack2(float a, float b) {
    return (unsigned int)f2bf(a) | ((unsigned int)f2bf(b) << 16);
}

// ---------- canonicalize weights only + deg_init (extra blocks) ----------
struct SP { const void* q[25]; };
__global__ __launch_bounds__(256) void convert_k(SP sp, unsigned short* __restrict__ canon,
                                                 int* __restrict__ deg) {
    if (blockIdx.x >= CONV_W_BLKS) {
        int i = (blockIdx.x - CONV_W_BLKS) * 256 + threadIdx.x;
        if (i < N_NODES) deg[i] = 1;   // self-loop
        return;
    }
    int i = blockIdx.x * 256 + threadIdx.x + OFF_EW1;
    if (i >= CANON_TOT) return;
    int fl = dtype_flag((const unsigned short*)sp.q[3]);   // enc_g
    int t = 1;
    while (i >= c_off[t + 1]) ++t;
    int j = i - c_off[t];
    const void* s = sp.q[t];
    canon[i] = fl == 0 ? ((const unsigned short*)s)[j] : f2bf(((const float*)s)[j]);
}

// ---------- weight transposes + layer-0 logit projection P0 = W0·a (64x8) ----------
__global__ void wt_k(const unsigned short* __restrict__ canon,
                     unsigned short* __restrict__ wt0, unsigned short* __restrict__ wt1,
                     unsigned short* __restrict__ wt2, unsigned short* __restrict__ w1t,
                     unsigned short* __restrict__ w2t, unsigned short* __restrict__ p0) {
    int i = blockIdx.x * 256 + threadIdx.x;   // 65536 threads
    if (i < 8192) {
        int k = i >> 6, n = i & 63;
        w1t[n * 128 + k] = canon[OFF_EW1 + k * 64 + n];
    }
    if (i < 4096) {
        int k = i >> 6, n = i & 63;
        w2t[n * 64 + k] = canon[OFF_EW2 + k * 64 + n];
    }
    if (i < 16384) {
        int k = i >> 8, n = i & 255;
        wt0[n * 64 + k] = canon[OFF_C0W + i];
    }
    if (i < 65536) {
        int k = i >> 8, n = i & 255;
        wt1[n * 256 + k] = canon[OFF_C1W + i];
        wt2[n * 256 + k] = canon[OFF_C2W + i];
    }
    if (i < 512) {   // P0[k][out], out = sd*4+h
        int out = i & 7, k = i >> 3;
        int h = out & 3, sd = out >> 2;
        int abase = (sd == 0 ? OFF_C0AS : OFF_C0AD) + h * 64;
        int wbase = OFF_C0W + k * 256 + h * 64;
        float s = 0.f;
        for (int c = 0; c < 64; ++c)
            s = fmaf(bf2f(canon[wbase + c]), bf2f(canon[abase + c]), s);
        p0[k * 8 + out] = f2bf(s);
    }
}

// ---------------- fused encoder: h0 = relu(LN(x@w1+b1))@w2+b2, x read direct (dtype branch) ----------------
__global__ __launch_bounds__(128) void enc_k(const void* __restrict__ xraw,
                                             const unsigned short* __restrict__ canon,
                                             const unsigned short* __restrict__ w1t,
                                             const unsigned short* __restrict__ w2t,
                                             const unsigned short* __restrict__ p0,
                                             const unsigned short* __restrict__ encg,
                                             unsigned short* __restrict__ h0,
                                             float* __restrict__ alS, float* __restrict__ alD) {
    __shared__ unsigned short As[128 * 72];
    __shared__ unsigned short Bs[64 * 72];
    int tid = threadIdx.x, wave = tid >> 6, lane = tid & 63;
    int q = lane >> 4, l = lane & 15;
    int row0 = blockIdx.x * 128;
    int fl = dtype_flag(encg);   // wave-uniform
    const unsigned short* xbf = (const unsigned short*)xraw;
    const float* xf = (const float*)xraw;
    // ---- GEMM1: T1pre = x @ w1 ----
    f32x4 acc[4][4];
#pragma unroll
    for (int a = 0; a < 4; ++a)
#pragma unroll
        for (int b = 0; b < 4; ++b) acc[a][b] = (f32x4){0.f, 0.f, 0.f, 0.f};
    for (int kb = 0; kb < IN_F; kb += 64) {
#pragma unroll
        for (int it = 0; it < 8; ++it) {
            int cid = it * 128 + tid;
            int r = cid >> 3, kc = cid & 7;
            int gr = row0 + r;
            uint4 v = make_uint4(0, 0, 0, 0);
            if (gr < N_NODES) {
                if (fl == 0) {
                    v = *(const uint4*)(xbf + (size_t)gr * IN_F + kb + kc * 8);
                } else {
                    const float* xs = xf + (size_t)gr * IN_F + kb + kc * 8;
                    float4 f0 = *(const float4*)xs;
                    float4 f1 = *(const float4*)(xs + 4);
                    v.x = pack2(f0.x, f0.y); v.y = pack2(f0.z, f0.w);
                    v.z = pack2(f1.x, f1.y); v.w = pack2(f1.z, f1.w);
                }
            }
            *(uint4*)&As[r * 72 + kc * 8] = v;
        }
#pragma unroll
        for (int it = 0; it < 4; ++it) {
            int cid = it * 128 + tid;
            int r = cid >> 3, kc = cid & 7;
            uint4 w = *(const uint4*)(w1t + (size_t)r * IN_F + kb + kc * 8);
            *(uint4*)&Bs[r * 72 + kc * 8] = w;
        }
        __syncthreads();
#pragma unroll
        for (int ks = 0; ks < 64; ks += 32) {
            bf16x8 af[4], bfr[4];
#pragma unroll
            for (int mt = 0; mt < 4; ++mt)
                af[mt] = *(const bf16x8*)&As[(wave * 64 + mt * 16 + l) * 72 + ks + q * 8];
#pragma unroll
            for (int nt = 0; nt < 4; ++nt)
                bfr[nt] = *(const bf16x8*)&Bs[(nt * 16 + l) * 72 + ks + q * 8];
#pragma unroll
            for (int mt = 0; mt < 4; ++mt)
#pragma unroll
                for (int nt = 0; nt < 4; ++nt)
                    acc[mt][nt] = __builtin_amdgcn_mfma_f32_16x16x32_bf16(
                        af[mt], bfr[nt], acc[mt][nt], 0, 0, 0);
        }
        __syncthreads();
    }
    // ---- epilogue1: bias + LN + relu -> T1 tile into As (stride 72) ----
    float b1c[4], gc[4], bec[4];
#pragma unroll
    for (int nt = 0; nt < 4; ++nt) {
        int c = nt * 16 + l;
        b1c[nt] = bf2f(canon[OFF_EB1 + c]);
        gc[nt]  = bf2f(canon[OFF_EG + c]);
        bec[nt] = bf2f(canon[OFF_EBE + c]);
    }
#pragma unroll
    for (int mt = 0; mt < 4; ++mt) {
#pragma unroll
        for (int r = 0; r < 4; ++r) {
            int lr = wave * 64 + mt * 16 + q * 4 + r;
            float v0 = acc[mt][0][r] + b1c[0];
            float v1 = acc[mt][1][r] + b1c[1];
            float v2 = acc[mt][2][r] + b1c[2];
            float v3 = acc[mt][3][r] + b1c[3];
            float s = v0 + v1 + v2 + v3;
#pragma unroll
            for (int off = 1; off < 16; off <<= 1) s += __shfl_xor(s, off);
            float mean = s * (1.0f / 64.0f);
            float d0 = v0 - mean, d1 = v1 - mean, d2 = v2 - mean, d3 = v3 - mean;
            float vs = d0 * d0 + d1 * d1 + d2 * d2 + d3 * d3;
#pragma unroll
            for (int off = 1; off < 16; off <<= 1) vs += __shfl_xor(vs, off);
            float rstd = rsqrtf(vs * (1.0f / 64.0f) + LNEPS);
            float o0 = gc[0] * d0 * rstd + bec[0]; o0 = fmaxf(o0, 0.f);
            float o1 = gc[1] * d1 * rstd + bec[1]; o1 = fmaxf(o1, 0.f);
            float o2 = gc[2] * d2 * rstd + bec[2]; o2 = fmaxf(o2, 0.f);
            float o3 = gc[3] * d3 * rstd + bec[3]; o3 = fmaxf(o3, 0.f);
            As[lr * 72 + l] = f2bf(o0);
            As[lr * 72 + 16 + l] = f2bf(o1);
            As[lr * 72 + 32 + l] = f2bf(o2);
            As[lr * 72 + 48 + l] = f2bf(o3);
        }
    }
    // ---- stage w2t into Bs ----
#pragma unroll
    for (int it = 0; it < 4; ++it) {
        int cid = it * 128 + tid;
        int r = cid >> 3, kc = cid & 7;
        uint4 w = *(const uint4*)(w2t + (size_t)r * HIDF + kc * 8);
        *(uint4*)&Bs[r * 72 + kc * 8] = w;
    }
    __syncthreads();
    // ---- GEMM2: h0 = T1 @ w2 ----
    f32x4 acc2[4][4];
#pragma unroll
    for (int a = 0; a < 4; ++a)
#pragma unroll
        for (int b = 0; b < 4; ++b) acc2[a][b] = (f32x4){0.f, 0.f, 0.f, 0.f};
#pragma unroll
    for (int ks = 0; ks < 64; ks += 32) {
        bf16x8 af[4], bfr[4];
#pragma unroll
        for (int mt = 0; mt < 4; ++mt)
            af[mt] = *(const bf16x8*)&As[(wave * 64 + mt * 16 + l) * 72 + ks + q * 8];
#pragma unroll
        for (int nt = 0; nt < 4; ++nt)
            bfr[nt] = *(const bf16x8*)&Bs[(nt * 16 + l) * 72 + ks + q * 8];
#pragma unroll
        for (int mt = 0; mt < 4; ++mt)
#pragma unroll
            for (int nt = 0; nt < 4; ++nt)
                acc2[mt][nt] = __builtin_amdgcn_mfma_f32_16x16x32_bf16(
                    af[mt], bfr[nt], acc2[mt][nt], 0, 0, 0);
    }
    float b2c[4];
#pragma unroll
    for (int nt = 0; nt < 4; ++nt) b2c[nt] = bf2f(canon[OFF_EB2 + nt * 16 + l]);
    __syncthreads();   // done reading As(T1)/Bs(w2t)
    // ---- stage h0 tile into As, p0 floats into Bs ----
#pragma unroll
    for (int mt = 0; mt < 4; ++mt) {
#pragma unroll
        for (int r = 0; r < 4; ++r) {
            int lr = wave * 64 + mt * 16 + q * 4 + r;
#pragma unroll
            for (int nt = 0; nt < 4; ++nt)
                As[lr * 72 + nt * 16 + l] = f2bf(acc2[mt][nt][r] + b2c[nt]);
        }
    }
    float* p0f = (float*)Bs;
    for (int i = tid; i < 512; i += 128) p0f[i] = bf2f(p0[i]);
    __syncthreads();
    // ---- one thread per row: store h0 + 8 logits ----
    int row = tid, grow = row0 + row;
    if (grow < N_NODES) {
        const unsigned short* srow = &As[row * 72];
        unsigned short* hrow = h0 + (size_t)grow * HIDF;
#pragma unroll
        for (int i = 0; i < 8; ++i)
            *(uint4*)(hrow + i * 8) = *(const uint4*)(srow + i * 8);
        float s[8] = {};
#pragma unroll
        for (int k = 0; k < 64; ++k) {
            float hv = bf2f(srow[k]);
            const float* pp = &p0f[k * 8];
#pragma unroll
            for (int o = 0; o < 8; ++o) s[o] = fmaf(hv, pp[o], s[o]);
        }
#pragma unroll
        for (int h = 0; h < 4; ++h) {
            alS[(size_t)grow * 4 + h] = s[h];
            alD[(size_t)grow * 4 + h] = s[4 + h];
        }
    }
}

// ---------------- CSR build ----------------
__global__ void deg_count_k(const int* __restrict__ dstI, int* __restrict__ deg) {
    int i = blockIdx.x * 256 + threadIdx.x;
    if (i < E_EDGES) atomicAdd(&deg[dstI[i]], 1);
}
__global__ __launch_bounds__(256) void scan1_k(const int* __restrict__ deg, int* __restrict__ excl,
                                               int* __restrict__ bsums) {
    int tid = threadIdx.x, lane = tid & 63, wv = tid >> 6;
    int gid = blockIdx.x * 256 + tid;
    int v = (gid < N_NODES) ? deg[gid] : 0;
    int inc = v;
#pragma unroll
    for (int off = 1; off < 64; off <<= 1) { int t = __shfl_up(inc, off); if (lane >= off) inc += t; }
    __shared__ int wsum[4];
    if (lane == 63) wsum[wv] = inc;
    __syncthreads();
    int wo = 0;
    for (int w = 0; w < wv; ++w) wo += wsum[w];
    int incl = inc + wo;
    if (gid < N_NODES) excl[gid] = incl - v;
    if (tid == 255) bsums[blockIdx.x] = incl;
}
__global__ __launch_bounds__(256) void scan2_k(const int* __restrict__ bsums, int* __restrict__ boff,
                                               int* __restrict__ totalp) {
    int tid = threadIdx.x, lane = tid & 63, wv = tid >> 6;
    int v = (tid < NB256) ? bsums[tid] : 0;
    int inc = v;
#pragma unroll
    for (int off = 1; off < 64; off <<= 1) { int t = __shfl_up(inc, off); if (lane >= off) inc += t; }
    __shared__ int wsum[4];
    if (lane == 63) wsum[wv] = inc;
    __syncthreads();
    int wo = 0;
    for (int w = 0; w < wv; ++w) wo += wsum[w];
    int incl = inc + wo;
    if (tid < NB256) boff[tid] = incl - v;
    if (tid == 255) *totalp = incl;
}
__global__ void scan3_k(const int* __restrict__ excl, const int* __restrict__ boff,
                        int* __restrict__ rowp, int* __restrict__ cursor) {
    int i = blockIdx.x * 256 + threadIdx.x;
    if (i < N_NODES) { int r = excl[i] + boff[i >> 8]; rowp[i] = r; cursor[i] = r; }
}
__global__ void fill_k(const int* __restrict__ srcI, const int* __restrict__ dstI,
                       int* __restrict__ cursor, int* __restrict__ colx) {
    int i = blockIdx.x * 256 + threadIdx.x;
    if (i >= E_EDGES + N_NODES) return;
    int s, d;
    if (i < E_EDGES) { s = srcI[i]; d = dstI[i]; } else { s = i - E_EDGES; d = s; }
    int slot = atomicAdd(&cursor[d], 1);
    colx[slot] = s;
}

// ---------------- layer-0 aggregate in 64-dim h0 space ----------------
__global__ __launch_bounds__(256) void agg0_k(
    const unsigned short* __restrict__ h0, const int* __restrict__ rowp, const int* __restrict__ colx,
    const float* __restrict__ alS, const float* __restrict__ alD,
    unsigned short* __restrict__ z0) {
    int tid = threadIdx.x, wave = tid >> 6, lane = tid & 63;
    int n = blockIdx.x * 4 + wave;
    if (n >= N_NODES) return;
    int start = rowp[n], end = rowp[n + 1];
    int e = lane >> 5;
    int c = lane & 31;
    int head = c >> 3;
    float adh = alD[(size_t)n * 4 + head];
    float a0 = 0.f, a1 = 0.f, asum = 0.f;
    int j = start;
    for (; j + 7 < end; j += 8) {
        int ja = j + e, jb = j + 2 + e, jc2 = j + 4 + e, jd = j + 6 + e;
        int sa = colx[ja], sb = colx[jb], sc = colx[jc2], sd = colx[jd];
        float ea = alS[(size_t)sa * 4 + head] + adh; ea = ea > 0.f ? ea : NEG * ea;
        float eb = alS[(size_t)sb * 4 + head] + adh; eb = eb > 0.f ? eb : NEG * eb;
        float ec = alS[(size_t)sc * 4 + head] + adh; ec = ec > 0.f ? ec : NEG * ec;
        float ed = alS[(size_t)sd * 4 + head] + adh; ed = ed > 0.f ? ed : NEG * ed;
        float wa = __expf(ea), wb = __expf(eb), wc = __expf(ec), wd = __expf(ed);
        unsigned int ua = *(const unsigned int*)(h0 + (size_t)sa * HIDF + c * 2);
        unsigned int ub = *(const unsigned int*)(h0 + (size_t)sb * HIDF + c * 2);
        unsigned int uc = *(const unsigned int*)(h0 + (size_t)sc * HIDF + c * 2);
        unsigned int ud = *(const unsigned int*)(h0 + (size_t)sd * HIDF + c * 2);
        asum += (wa + wb) + (wc + wd);
        a0 = fmaf(wa, bf2f((unsigned short)(ua & 0xffff)), a0);
        a1 = fmaf(wa, bf2f((unsigned short)(ua >> 16)),    a1);
        a0 = fmaf(wb, bf2f((unsigned short)(ub & 0xffff)), a0);
        a1 = fmaf(wb, bf2f((unsigned short)(ub >> 16)),    a1);
        a0 = fmaf(wc, bf2f((unsigned short)(uc & 0xffff)), a0);
        a1 = fmaf(wc, bf2f((unsigned short)(uc >> 16)),    a1);
        a0 = fmaf(wd, bf2f((unsigned short)(ud & 0xffff)), a0);
        a1 = fmaf(wd, bf2f((unsigned short)(ud >> 16)),    a1);
    }
    for (; j < end; j += 2) {
        int j1 = j + e;
        int jc = j1 < end ? j1 : end - 1;
        int s1 = colx[jc];
        float w1 = 0.f;
        if (j1 < end) {
            float ev = alS[(size_t)s1 * 4 + head] + adh;
            ev = ev > 0.f ? ev : NEG * ev;
            w1 = __expf(ev);
        }
        unsigned int u1 = *(const unsigned int*)(h0 + (size_t)s1 * HIDF + c * 2);
        asum += w1;
        a0 = fmaf(w1, bf2f((unsigned short)(u1 & 0xffff)), a0);
        a1 = fmaf(w1, bf2f((unsigned short)(u1 >> 16)),    a1);
    }
    a0 += __shfl_xor(a0, 32);
    a1 += __shfl_xor(a1, 32);
    asum += __shfl_xor(asum, 32);
    if (lane < 32) {
        float rh = 1.f / (asum + 1e-16f);
        unsigned int o = (unsigned int)f2bf(a0 * rh) | ((unsigned int)f2bf(a1 * rh) << 16);
        *(unsigned int*)(z0 + (size_t)n * HIDF + c * 2) = o;
    }
}

// ---------------- MFMA matmul; optional bias+ELU; optional fused logits ----------------
__global__ __launch_bounds__(256) void mfma_mm_k(
    const unsigned short* __restrict__ A, const unsigned short* __restrict__ Wt,
    unsigned short* __restrict__ C, int M, int K,
    const unsigned short* __restrict__ bias,
    const unsigned short* __restrict__ aSv, const unsigned short* __restrict__ aDv,
    float* __restrict__ alS, float* __restrict__ alD) {
    __shared__ unsigned short smem[128 * 72 * 2];   // As | Bs; reused as C-tile (128x136)
    unsigned short* As = smem;
    unsigned short* Bs = smem + 128 * 72;
    int tid = threadIdx.x;
    int wave = tid >> 6, lane = tid & 63;
    int wm = wave >> 1, wn = wave & 1;
    int row0 = blockIdx.y * 128, col0 = blockIdx.x * 128;
    int q = lane >> 4, l = lane & 15;
    f32x4 acc[4][4];
#pragma unroll
    for (int a = 0; a < 4; ++a)
#pragma unroll
        for (int b = 0; b < 4; ++b) acc[a][b] = (f32x4){0.f, 0.f, 0.f, 0.f};
    for (int kb = 0; kb < K; kb += 64) {
#pragma unroll
        for (int it = 0; it < 4; ++it) {
            int cid = it * 256 + tid;
            int r = cid >> 3, kc = cid & 7;
            int gr = row0 + r;
            uint4 v = make_uint4(0, 0, 0, 0);
            if (gr < M) v = *(const uint4*)(A + (size_t)gr * K + kb + kc * 8);
            *(uint4*)&As[r * 72 + kc * 8] = v;
            int gn = col0 + r;
            uint4 w = *(const uint4*)(Wt + (size_t)gn * K + kb + kc * 8);
            *(uint4*)&Bs[r * 72 + kc * 8] = w;
        }
        __syncthreads();
#pragma unroll
        for (int ks = 0; ks < 64; ks += 32) {
            bf16x8 af[4], bfr[4];
#pragma unroll
            for (int mt = 0; mt < 4; ++mt)
                af[mt] = *(const bf16x8*)&As[(wm * 64 + mt * 16 + l) * 72 + ks + q * 8];
#pragma unroll
            for (int nt = 0; nt < 4; ++nt)
                bfr[nt] = *(const bf16x8*)&Bs[(wn * 64 + nt * 16 + l) * 72 + ks + q * 8];
#pragma unroll
            for (int mt = 0; mt < 4; ++mt)
#pragma unroll
                for (int nt = 0; nt < 4; ++nt)
                    acc[mt][nt] = __builtin_amdgcn_mfma_f32_16x16x32_bf16(
                        af[mt], bfr[nt], acc[mt][nt], 0, 0, 0);
        }
        __syncthreads();
    }
    float bv[4] = {0.f, 0.f, 0.f, 0.f};
    bool doBias = (bias != nullptr);
    if (doBias) {
#pragma unroll
        for (int nt = 0; nt < 4; ++nt)
            bv[nt] = bf2f(bias[col0 + wn * 64 + nt * 16 + l]);
    }
#pragma unroll
    for (int mt = 0; mt < 4; ++mt) {
        int rowb = wm * 64 + mt * 16 + q * 4;
#pragma unroll
        for (int r = 0; r < 4; ++r) {
#pragma unroll
            for (int nt = 0; nt < 4; ++nt) {
                float v = acc[mt][nt][r];
                if (doBias) { v += bv[nt]; v = v > 0.f ? v : __expf(v) - 1.f; }
                smem[(rowb + r) * 136 + wn * 64 + nt * 16 + l] = f2bf(v);
            }
        }
    }
    __syncthreads();
    int row = tid >> 1, half = tid & 1;
    int grow = row0 + row;
    if (grow < M) {
        unsigned short* crow = C + (size_t)grow * D_F + col0 + half * 64;
        const unsigned short* srow = &smem[row * 136 + half * 64];
#pragma unroll
        for (int i = 0; i < 8; ++i)
            *(uint4*)(crow + i * 8) = *(const uint4*)(srow + i * 8);
        if (aSv != nullptr) {
            int head = (col0 >> 6) + half;
            const unsigned short* av = aSv + head * 64;
            const unsigned short* dv = aDv + head * 64;
            float ps = 0.f, pd = 0.f;
#pragma unroll
            for (int k = 0; k < 64; ++k) {
                float hv = bf2f(srow[k]);
                ps = fmaf(hv, bf2f(av[k]), ps);
                pd = fmaf(hv, bf2f(dv[k]), pd);
            }
            alS[(size_t)grow * 4 + head] = ps;
            alD[(size_t)grow * 4 + head] = pd;
        }
    }
}

// ---------------- fused GAT aggregate (256-dim): 8-edge loop, 4 loads in flight ----------------
__global__ __launch_bounds__(256) void agg_k(
    const unsigned short* __restrict__ h2, const int* __restrict__ rowp, const int* __restrict__ colx,
    const float* __restrict__ alS, const float* __restrict__ alD,
    const unsigned short* __restrict__ bias, unsigned short* __restrict__ out) {
    int tid = threadIdx.x, wave = tid >> 6, lane = tid & 63;
    int n = blockIdx.x * 4 + wave;
    if (n >= N_NODES) return;
    int start = rowp[n], end = rowp[n + 1];
    int e = lane >> 5;
    int c = lane & 31;
    int head = c >> 3;
    float adh = alD[(size_t)n * 4 + head];
    float acc[8] = {};
    float asum = 0.f;
    int j = start;
    for (; j + 7 < end; j += 8) {
        int ja = j + e, jb = j + 2 + e, jc2 = j + 4 + e, jd = j + 6 + e;
        int sa = colx[ja], sb = colx[jb], sc = colx[jc2], sd = colx[jd];
        float ea = alS[(size_t)sa * 4 + head] + adh; ea = ea > 0.f ? ea : NEG * ea;
        float eb = alS[(size_t)sb * 4 + head] + adh; eb = eb > 0.f ? eb : NEG * eb;
        float ec = alS[(size_t)sc * 4 + head] + adh; ec = ec > 0.f ? ec : NEG * ec;
        float ed = alS[(size_t)sd * 4 + head] + adh; ed = ed > 0.f ? ed : NEG * ed;
        float wa = __expf(ea), wb = __expf(eb), wc = __expf(ec), wd = __expf(ed);
        uint4 ua = *(const uint4*)(h2 + (size_t)sa * D_F + c * 8);
        uint4 ub = *(const uint4*)(h2 + (size_t)sb * D_F + c * 8);
        uint4 uc = *(const uint4*)(h2 + (size_t)sc * D_F + c * 8);
        uint4 ud = *(const uint4*)(h2 + (size_t)sd * D_F + c * 8);
        asum += (wa + wb) + (wc + wd);
        mac8(acc, wa, ua);
        mac8(acc, wb, ub);
        mac8(acc, wc, uc);
        mac8(acc, wd, ud);
    }
    for (; j < end; j += 2) {
        int j1 = j + e;
        int jc = j1 < end ? j1 : end - 1;
        int s1 = colx[jc];
        float w1 = 0.f;
        if (j1 < end) {
            float ev = alS[(size_t)s1 * 4 + head] + adh;
            ev = ev > 0.f ? ev : NEG * ev;
            w1 = __expf(ev);
        }
        uint4 u1 = *(const uint4*)(h2 + (size_t)s1 * D_F + c * 8);
        asum += w1;
        mac8(acc, w1, u1);
    }
#pragma unroll
    for (int k = 0; k < 8; ++k) acc[k] += __shfl_xor(acc[k], 32);
    asum += __shfl_xor(asum, 32);
    if (lane < 32) {
        float rh = 1.f / (asum + 1e-16f);
        uint4 bu = *(const uint4*)(bias + c * 8);
        float b[8];
        b[0] = bf2f((unsigned short)(bu.x & 0xffff)); b[1] = bf2f((unsigned short)(bu.x >> 16));
        b[2] = bf2f((unsigned short)(bu.y & 0xffff)); b[3] = bf2f((unsigned short)(bu.y >> 16));
        b[4] = bf2f((unsigned short)(bu.z & 0xffff)); b[5] = bf2f((unsigned short)(bu.z >> 16));
        b[6] = bf2f((unsigned short)(bu.w & 0xffff)); b[7] = bf2f((unsigned short)(bu.w >> 16));
        unsigned int o[4];
#pragma unroll
        for (int k = 0; k < 4; ++k) {
            float v0 = acc[2 * k] * rh + b[2 * k];
            float v1 = acc[2 * k + 1] * rh + b[2 * k + 1];
            v0 = v0 > 0.f ? v0 : __expf(v0) - 1.f;
            v1 = v1 > 0.f ? v1 : __expf(v1) - 1.f;
            o[k] = (unsigned int)f2bf(v0) | ((unsigned int)f2bf(v1) << 16);
        }
        *(uint4*)(out + (size_t)n * D_F + c * 8) = make_uint4(o[0], o[1], o[2], o[3]);
    }
}

// ---------------- pool: batch sorted -> register accumulation, flush on group change ----------------
__global__ __launch_bounds__(256) void pool_k(const unsigned short* __restrict__ h,
                                              const int* __restrict__ batch,
                                              float* __restrict__ part, int* __restrict__ pcnt) {
    __shared__ float sums[GROUPS * D_F];
    __shared__ int cnts[GROUPS];
    int tid = threadIdx.x, wave = tid >> 6, lane = tid & 63;
    for (int i = tid; i < GROUPS * D_F; i += 256) sums[i] = 0.f;
    if (tid < GROUPS) cnts[tid] = 0;
    __syncthreads();
    int n0 = blockIdx.x * POOL_CHUNK + wave * (POOL_CHUNK / 4);
    int n1 = n0 + POOL_CHUNK / 4; if (n1 > N_NODES) n1 = N_NODES;
    float a0 = 0.f, a1 = 0.f, a2 = 0.f, a3 = 0.f;
    int curb = -1, cnt = 0;
    for (int n = n0; n < n1; ++n) {
        int b = batch[n];
        if (b != curb) {
            if (curb >= 0) {
                atomicAdd(&sums[curb * D_F + lane * 4 + 0], a0);
                atomicAdd(&sums[curb * D_F + lane * 4 + 1], a1);
                atomicAdd(&sums[curb * D_F + lane * 4 + 2], a2);
                atomicAdd(&sums[curb * D_F + lane * 4 + 3], a3);
                if (lane == 0) atomicAdd(&cnts[curb], cnt);
            }
            a0 = a1 = a2 = a3 = 0.f; cnt = 0; curb = b;
        }
        uint2 u = *(const uint2*)(h + (size_t)n * D_F + lane * 4);
        a0 += bf2f((unsigned short)(u.x & 0xffff));
        a1 += bf2f((unsigned short)(u.x >> 16));
        a2 += bf2f((unsigned short)(u.y & 0xffff));
        a3 += bf2f((unsigned short)(u.y >> 16));
        ++cnt;
    }
    if (curb >= 0) {
        atomicAdd(&sums[curb * D_F + lane * 4 + 0], a0);
        atomicAdd(&sums[curb * D_F + lane * 4 + 1], a1);
        atomicAdd(&sums[curb * D_F + lane * 4 + 2], a2);
        atomicAdd(&sums[curb * D_F + lane * 4 + 3], a3);
        if (lane == 0) atomicAdd(&cnts[curb], cnt);
    }
    __syncthreads();
    float* po = part + (size_t)blockIdx.x * (GROUPS * D_F);
    for (int i = tid; i < GROUPS * D_F; i += 256) po[i] = sums[i];
    if (tid < GROUPS) pcnt[blockIdx.x * GROUPS + tid] = cnts[tid];
}

// ---------------- reduce ----------------
__global__ __launch_bounds__(256) void reduce_k(const float* __restrict__ part,
                                                const int* __restrict__ pcnt,
                                                float* __restrict__ gsum, int* __restrict__ gcnt) {
    int g = blockIdx.x, c = threadIdx.x;
    float s = 0.f;
    for (int b = 0; b < POOL_BLOCKS; ++b) s += part[(size_t)b * (GROUPS * D_F) + g * D_F + c];
    gsum[g * D_F + c] = s;
    if (threadIdx.x < 64) {
        int lane = threadIdx.x;
        int cn = 0;
        for (int b = lane; b < POOL_BLOCKS; b += 64) cn += pcnt[b * GROUPS + g];
#pragma unroll
        for (int off = 1; off < 64; off <<= 1) cn += __shfl_xor(cn, off);
        if (lane == 0) gcnt[g] = cn;
    }
}

// ---------------- decoder ----------------
__global__ __launch_bounds__(256) void dec_k(const float* __restrict__ gsum, const int* __restrict__ gcnt,
    const unsigned short* __restrict__ canon, const unsigned short* __restrict__ encg,
    void* __restrict__ outp) {
    const unsigned short* w1 = canon + OFF_DW1;
    const unsigned short* b1 = canon + OFF_DB1;
    const unsigned short* gam = canon + OFF_DG;
    const unsigned short* bet = canon + OFF_DBE;
    const unsigned short* w2 = canon + OFF_DW2;
    const unsigned short* b2 = canon + OFF_DB2;
    int tid = threadIdx.x, grp = blockIdx.x * 4 + (tid >> 6), lane = tid & 63;
    if (grp >= GROUPS) return;
    float inv = 1.0f / fmaxf((float)gcnt[grp], 1.0f);
    float p[4];
#pragma unroll
    for (int i = 0; i < 4; ++i) p[i] = gsum[grp * D_F + i * 64 + lane] * inv;
    float acc = bf2f(b1[lane]);
#pragma unroll
    for (int i = 0; i < 4; ++i)
        for (int k = 0; k < 64; ++k)
            acc = fmaf(__shfl(p[i], k), bf2f(w1[(i * 64 + k) * 64 + lane]), acc);
    float s = acc;
#pragma unroll
    for (int off = 32; off > 0; off >>= 1) s += __shfl_xor(s, off);
    float mean = s * (1.0f / 64.0f);
    float d = acc - mean;
    float vs = d * d;
#pragma unroll
    for (int off = 32; off > 0; off >>= 1) vs += __shfl_xor(vs, off);
    float rstd = rsqrtf(vs * (1.0f / 64.0f) + LNEPS);
    float val = bf2f(gam[lane]) * d * rstd + bf2f(bet[lane]);
    val = val > 0.f ? val : val * 0.f;
    int cl = (lane < OUT_F) ? lane : 0;
    float acc2 = 0.f;
    for (int k = 0; k < 64; ++k) {
        float wv = bf2f(w2[k * OUT_F + cl]);
        acc2 = fmaf(__shfl(val, k), wv, acc2);
    }
    if (lane < OUT_F) {
        float res = acc2 + bf2f(b2[lane]);
        if (dtype_flag(encg) == 0) ((unsigned short*)outp)[grp * OUT_F + lane] = f2bf(res);
        else                       ((float*)outp)[grp * OUT_F + lane] = res;
    }
}

extern "C" void kernel_launch(void* const* d_in, const int* in_sizes, int n_in,
                              void* d_out, int out_size, void* d_ws, size_t ws_size,
                              hipStream_t stream) {
    const int* ei    = (const int*)d_in[1];
    const int* batch = (const int*)d_in[2];

    char* p = (char*)d_ws;
    unsigned short* canon = (unsigned short*)p; p += (size_t)CANON_TOT * 2 + 16;
    unsigned short* bufA = (unsigned short*)p; p += (size_t)N_NODES * D_F * 2;
    unsigned short* bufB = (unsigned short*)p; p += (size_t)N_NODES * D_F * 2;
    unsigned short* zbuf = (unsigned short*)p; p += (size_t)N_NODES * HIDF * 2;
    unsigned short* wt0 = (unsigned short*)p; p += (size_t)64 * 256 * 2;
    unsigned short* wt1 = (unsigned short*)p; p += (size_t)256 * 256 * 2;
    unsigned short* wt2 = (unsigned short*)p; p += (size_t)256 * 256 * 2;
    unsigned short* w1t = (unsigned short*)p; p += (size_t)64 * 128 * 2;
    unsigned short* w2t = (unsigned short*)p; p += (size_t)64 * 64 * 2;
    unsigned short* p0  = (unsigned short*)p; p += (size_t)64 * 8 * 2 + 16;
    float* alS  = (float*)p; p += (size_t)N_NODES * 4 * 4;
    float* alD  = (float*)p; p += (size_t)N_NODES * 4 * 4;
    float* part = (float*)p; p += (size_t)POOL_BLOCKS * GROUPS * D_F * 4;
    int* pcnt   = (int*)p;   p += (size_t)POOL_BLOCKS * GROUPS * 4;
    float* gsum = (float*)p; p += GROUPS * D_F * 4;
    int* gcnt   = (int*)p;   p += 16 * 4;
    int* deg    = (int*)p;   p += (size_t)N_NODES * 4;
    int* excl   = (int*)p;   p += (size_t)N_NODES * 4;
    int* bsums  = (int*)p;   p += 256 * 4;
    int* boff   = (int*)p;   p += 256 * 4;
    int* rowp   = (int*)p;   p += (size_t)(N_NODES + 4) * 4;
    int* cursor = (int*)p;   p += (size_t)N_NODES * 4;
    int* colx   = (int*)p;   p += (size_t)(E_EDGES + N_NODES) * 4;

    const int* srcI = ei;
    const int* dstI = ei + E_EDGES;
    const unsigned short* encg = (const unsigned short*)d_in[5];

    SP sp;
    sp.q[0] = d_in[0];
    for (int t = 1; t < 25; ++t) sp.q[t] = d_in[t + 2];

    int nwb = (N_NODES + 3) / 4;
    int nb128 = (N_NODES + 127) / 128;

    convert_k<<<CONV_W_BLKS + NB256, 256, 0, stream>>>(sp, canon, deg);   // weights + deg_init
    wt_k<<<256, 256, 0, stream>>>(canon, wt0, wt1, wt2, w1t, w2t, p0);
    deg_count_k<<<(E_EDGES + 255) / 256, 256, 0, stream>>>(dstI, deg);

    enc_k<<<nb128, 128, 0, stream>>>(d_in[0], canon, w1t, w2t, p0, encg, bufA, alS, alD);

    scan1_k<<<NB256, 256, 0, stream>>>(deg, excl, bsums);
    scan2_k<<<1, 256, 0, stream>>>(bsums, boff, rowp + N_NODES);
    scan3_k<<<NB256, 256, 0, stream>>>(excl, boff, rowp, cursor);
    fill_k<<<(E_EDGES + N_NODES + 255) / 256, 256, 0, stream>>>(srcI, dstI, cursor, colx);

    dim3 mmg(2, nb128);
    // layer 0 (swapped): aggregate h0 in 64-dim; then matmul w/ bias+ELU
    agg0_k<<<nwb, 256, 0, stream>>>(bufA, rowp, colx, alS, alD, zbuf);
    mfma_mm_k<<<mmg, 256, 0, stream>>>(zbuf, wt0, bufB, N_NODES, HIDF,
                                       canon + OFF_C0B, nullptr, nullptr, nullptr, nullptr);
    // layer 1
    mfma_mm_k<<<mmg, 256, 0, stream>>>(bufB, wt1, bufA, N_NODES, D_F,
                                       nullptr, canon + OFF_C1AS, canon + OFF_C1AD, alS, alD);
    agg_k<<<nwb, 256, 0, stream>>>(bufA, rowp, colx, alS, alD, canon + OFF_C1B, bufB);
    // layer 2
    mfma_mm_k<<<mmg, 256, 0, stream>>>(bufB, wt2, bufA, N_NODES, D_F,
                                       nullptr, canon + OFF_C2AS, canon + OFF_C2AD, alS, alD);
    agg_k<<<nwb, 256, 0, stream>>>(bufA, rowp, colx, alS, alD, canon + OFF_C2B, bufB);

    pool_k<<<POOL_BLOCKS, 256, 0, stream>>>(bufB, batch, part, pcnt);
    reduce_k<<<GROUPS, 256, 0, stream>>>(part, pcnt, gsum, gcnt);
    dec_k<<<2, 256, 0, stream>>>(gsum, gcnt, canon, encg, d_out);
}